// Round 4
// baseline (1262.429 us; speedup 1.0000x reference)
//
#include <hip/hip_runtime.h>

#define N_NODES 100000
#define N_EDGES 3200000
#define HD      32
#define NLAYERS 4
#define NGRAPHS 1000
#define BN_EPS  1e-5f
#define BSHIFT  9                         // 512-node buckets
#define NBUCK   ((N_NODES + 511) >> 9)    // 196
#define PCHUNK  8192                      // edges per partition block
#define NPB     ((N_EDGES + PCHUNK - 1) / PCHUNK)   // 391

typedef _Float16 f16;
typedef _Float16 f16x4 __attribute__((ext_vector_type(4)));

// ---------------- encoder: hh = f16(x*W_enc + b_enc)  (+ zero-init) -----------
__global__ __launch_bounds__(256) void k_encoder(
    const float* __restrict__ x, const float* __restrict__ W_enc,
    const float* __restrict__ b_enc, f16* __restrict__ hh,
    float* __restrict__ stats, float* __restrict__ pooled)
{
    int gid = blockIdx.x * 256 + threadIdx.x;        // over N*8 (4 ch each)
    if (gid < NLAYERS * 64)   stats[gid]  = 0.f;
    if (gid < NGRAPHS * HD)   pooled[gid] = 0.f;
    if (gid < N_NODES * 8) {
        int i = gid >> 3, c0 = (gid & 7) * 4;
        float xv = x[i];
        f16x4 r;
        #pragma unroll
        for (int k = 0; k < 4; ++k)
            r[k] = (f16)(xv * W_enc[c0 + k] + b_enc[c0 + k]);
        *(f16x4*)(hh + i * HD + c0) = r;
    }
}

// ---------------- deterministic radix partition (no global atomics) -----------
__global__ __launch_bounds__(256) void k_phist(const int* __restrict__ ei,
                                               int* __restrict__ pcnt)
{
    __shared__ int hist[256];
    int t = threadIdx.x, blk = blockIdx.x;
    hist[t] = 0;
    __syncthreads();
    int e0 = blk * PCHUNK, e1 = min(e0 + PCHUNK, N_EDGES);
    for (int e = e0 + t; e < e1; e += 256)
        atomicAdd(&hist[ei[N_EDGES + e] >> BSHIFT], 1);
    __syncthreads();
    pcnt[t * NPB + blk] = hist[t];
}

__global__ __launch_bounds__(256) void k_pscan(int* __restrict__ pcnt,
                                               int* __restrict__ boff,
                                               int* __restrict__ off)
{
    __shared__ int sc[2][256];
    int t = threadIdx.x;
    int base = t * NPB;
    int acc = 0;
    for (int b = 0; b < NPB; ++b) acc += pcnt[base + b];
    int pp = 0;
    sc[0][t] = acc;
    __syncthreads();
    for (int st = 1; st < 256; st <<= 1) {
        int v = sc[pp][t];
        if (t >= st) v += sc[pp][t - st];
        sc[pp ^ 1][t] = v;
        pp ^= 1;
        __syncthreads();
    }
    int excl = sc[pp][t] - acc;
    if (t < NBUCK) boff[t] = excl;
    if (t == NBUCK - 1) { boff[NBUCK] = excl + acc; off[N_NODES] = excl + acc; }
    int run = excl;
    for (int b = 0; b < NPB; ++b) {
        int v = pcnt[base + b];
        pcnt[base + b] = run;
        run += v;
    }
}

__global__ __launch_bounds__(256) void k_pscatter(const int* __restrict__ ei,
                                                  const int* __restrict__ pcnt,
                                                  unsigned int* __restrict__ ebuf)
{
    __shared__ int lcur[256];
    int t = threadIdx.x, blk = blockIdx.x;
    lcur[t] = pcnt[t * NPB + blk];
    __syncthreads();
    int e0 = blk * PCHUNK, e1 = min(e0 + PCHUNK, N_EDGES);
    for (int e = e0 + t; e < e1; e += 256) {
        int src = ei[e], dst = ei[N_EDGES + e];
        int b = dst >> BSHIFT;
        int pos = atomicAdd(&lcur[b], 1);            // LDS atomic: block-local
        ebuf[pos] = ((unsigned)src << BSHIFT) | (unsigned)(dst & 511);
    }
}

__global__ __launch_bounds__(512) void k_bfinal(const unsigned int* __restrict__ ebuf,
                                                const int* __restrict__ boff,
                                                int* __restrict__ off,
                                                int* __restrict__ csr)
{
    __shared__ int cnt[512], scanbuf[2][512], cur[512];
    int tid = threadIdx.x, b = blockIdx.x;
    int base = boff[b], nE = boff[b + 1] - base;
    cnt[tid] = 0;
    __syncthreads();
    for (int e = tid; e < nE; e += 512)
        atomicAdd(&cnt[ebuf[base + e] & 511], 1);
    __syncthreads();
    int pp = 0;
    scanbuf[0][tid] = cnt[tid];
    __syncthreads();
    for (int st = 1; st < 512; st <<= 1) {
        int v = scanbuf[pp][tid];
        if (tid >= st) v += scanbuf[pp][tid - st];
        scanbuf[pp ^ 1][tid] = v;
        pp ^= 1;
        __syncthreads();
    }
    int excl = scanbuf[pp][tid] - cnt[tid];
    cur[tid] = excl;
    int gnode = (b << BSHIFT) + tid;
    if (gnode < N_NODES) off[gnode] = base + excl;
    __syncthreads();
    for (int e = tid; e < nE; e += 512) {
        unsigned int p = ebuf[base + e];
        int pos = atomicAdd(&cur[p & 511], 1);
        csr[base + pos] = (int)(p >> BSHIFT);
    }
}

// ---------------- fused layer: barrier-free wave-per-pair, shfl MLP -----------
__global__ __launch_bounds__(256) void k_layer(
    const f16* __restrict__ hh, const int* __restrict__ off,
    const int* __restrict__ csr, const float* __restrict__ epsArr,
    const float* __restrict__ W1, const float* __restrict__ b1,
    const float* __restrict__ W2, const float* __restrict__ b2,
    f16* __restrict__ z2out, float* __restrict__ stats, int layer)
{
    __shared__ float W1s[1024], W2s[1024];
    __shared__ float red[8][32];
    int tid = threadIdx.x;
    const float* W1l = W1 + layer * 1024;
    const float* W2l = W2 + layer * 1024;
    for (int k = tid; k < 1024; k += 256) { W1s[k] = W1l[k]; W2s[k] = W2l[k]; }
    int lane = tid & 63, wave = tid >> 6;
    int c = lane & 31, half = lane >> 5;
    float b1c = b1[layer * 32 + c], b2c = b2[layer * 32 + c];
    float onePlusEps = 1.0f + epsArr[layer];
    __syncthreads();

    int gwave = blockIdx.x * 4 + wave;
    int nwaves = gridDim.x * 4;
    float lsum = 0.f, lsq = 0.f;
    const int NPAIR = N_NODES / 2;                   // 50000

    for (int p = gwave; p < NPAIR; p += nwaves) {
        int node = p * 2 + half;
        int j = off[node], jend = off[node + 1];
        float a0 = 0.f, a1 = 0.f, a2 = 0.f, a3 = 0.f;
        while (j < jend && (j & 3)) a0 += (float)hh[csr[j++] * HD + c];
        int nb = (jend - j) >> 2;
        const int4* q = (const int4*)(csr + j);
        for (int it = 0; it < nb; ++it) {            // 4 independent gathers/iter
            int4 v = q[it];
            a0 += (float)hh[v.x * HD + c];
            a1 += (float)hh[v.y * HD + c];
            a2 += (float)hh[v.z * HD + c];
            a3 += (float)hh[v.w * HD + c];
        }
        j += nb << 2;
        while (j < jend) a0 += (float)hh[csr[j++] * HD + c];
        float z1 = onePlusEps * (float)hh[node * HD + c] + (a0 + a1) + (a2 + a3);

        float t = b1c;                               // MLP1 via cross-lane shfl
        #pragma unroll
        for (int k = 0; k < 32; ++k)
            t = fmaf(__shfl(z1, k, 32), W1s[k * 32 + c], t);
        t = fmaxf(t, 0.f);
        float z2 = b2c;                              // MLP2
        #pragma unroll
        for (int k = 0; k < 32; ++k)
            z2 = fmaf(__shfl(t, k, 32), W2s[k * 32 + c], z2);

        z2out[node * HD + c] = (f16)z2;
        lsum += z2; lsq += z2 * z2;
    }

    lsum += __shfl_xor(lsum, 32);                    // combine wave halves
    lsq  += __shfl_xor(lsq , 32);
    if (lane < 32) { red[wave * 2][c] = lsum; red[wave * 2 + 1][c] = lsq; }
    __syncthreads();
    if (tid < 64) {
        int sel = tid >> 5, cc = tid & 31;
        float s = 0.f;
        #pragma unroll
        for (int w = 0; w < 4; ++w) s += red[w * 2 + sel][cc];
        atomicAdd(&stats[layer * 64 + sel * 32 + cc], s);
    }
}

// ---------------- BatchNorm (batch stats) + ReLU -> hh -------------------------
__global__ __launch_bounds__(256) void k_bnapply(
    const f16* __restrict__ z2, const float* __restrict__ stats,
    const float* __restrict__ gamma, const float* __restrict__ beta,
    f16* __restrict__ hh, int layer)
{
    __shared__ float scs[32], shs[32];
    int t = threadIdx.x;
    if (t < 32) {
        const float invN = 1.0f / (float)N_NODES;
        float mu  = stats[layer * 64 + t] * invN;
        float var = stats[layer * 64 + 32 + t] * invN - mu * mu;
        float sc = gamma[layer * 32 + t] * rsqrtf(var + BN_EPS);
        scs[t] = sc;
        shs[t] = beta[layer * 32 + t] - mu * sc;
    }
    __syncthreads();
    int gid = blockIdx.x * 256 + t;                  // over N*HD/4
    if (gid >= N_NODES * HD / 4) return;
    int c0 = (gid * 4) & 31;
    f16x4 z = *(const f16x4*)(z2 + (size_t)gid * 4);
    f16x4 r;
    #pragma unroll
    for (int k = 0; k < 4; ++k)
        r[k] = (f16)fmaxf(fmaf((float)z[k], scs[c0 + k], shs[c0 + k]), 0.f);
    *(f16x4*)(hh + (size_t)gid * 4) = r;
}

// ---------------- global_add_pool (batch is sorted -> run-length reduce) -------
__global__ __launch_bounds__(256) void k_pool(const f16* __restrict__ hh,
                                              const int* __restrict__ batch,
                                              float* __restrict__ pooled)
{
    int c = threadIdx.x & 31, slot = threadIdx.x >> 5;
    int start = blockIdx.x * 256 + slot * 32;
    if (start >= N_NODES) return;
    int end = min(start + 32, N_NODES);
    int cur = batch[start]; float acc = 0.f;
    for (int i = start; i < end; ++i) {
        int g = batch[i];
        if (g != cur) { atomicAdd(&pooled[cur * HD + c], acc); acc = 0.f; cur = g; }
        acc += (float)hh[i * HD + c];
    }
    atomicAdd(&pooled[cur * HD + c], acc);
}

// ---------------- classifier ---------------------------------------------------
__global__ __launch_bounds__(256) void k_cls(const float* __restrict__ pooled,
                                             const float* __restrict__ Wc,
                                             const float* __restrict__ bc,
                                             float* __restrict__ out)
{
    int gid = blockIdx.x * 256 + threadIdx.x;
    if (gid >= NGRAPHS * 2) return;
    int g = gid >> 1, c = gid & 1;
    float s = bc[c];
    #pragma unroll
    for (int k = 0; k < 32; ++k) s = fmaf(pooled[g * 32 + k], Wc[k * 2 + c], s);
    out[gid] = s;
}

extern "C" void kernel_launch(void* const* d_in, const int* in_sizes, int n_in,
                              void* d_out, int out_size, void* d_ws, size_t ws_size,
                              hipStream_t stream)
{
    const float* x      = (const float*)d_in[0];
    const int*   ei     = (const int*)d_in[1];
    const int*   batch  = (const int*)d_in[2];
    const float* W_enc  = (const float*)d_in[3];
    const float* b_enc  = (const float*)d_in[4];
    const float* epsArr = (const float*)d_in[5];
    const float* W1     = (const float*)d_in[6];
    const float* b1     = (const float*)d_in[7];
    const float* W2     = (const float*)d_in[8];
    const float* b2     = (const float*)d_in[9];
    const float* gamma  = (const float*)d_in[10];
    const float* beta   = (const float*)d_in[11];
    const float* Wc     = (const float*)d_in[12];
    const float* bc     = (const float*)d_in[13];
    float* out = (float*)d_out;

    char* ws = (char*)d_ws;
    size_t o = 0;
    auto alloc = [&](size_t bytes) {
        char* p = ws + o;
        o += (bytes + 255) & ~(size_t)255;
        return p;
    };
    f16*   hh     = (f16*) alloc((size_t)N_NODES * HD * 2);    // 6.4 MB
    f16*   z2     = (f16*) alloc((size_t)N_NODES * HD * 2);    // 6.4 MB
    int*   csr    = (int*) alloc((size_t)N_EDGES * 4);         // 12.8 MB
    unsigned int* ebuf = (unsigned int*)alloc((size_t)N_EDGES * 4);  // 12.8 MB
    int*   offA   = (int*) alloc((size_t)(N_NODES + 1) * 4);
    int*   pcnt   = (int*) alloc((size_t)256 * NPB * 4);       // 0.4 MB
    int*   boff   = (int*) alloc(1024);
    float* stats  = (float*)alloc(NLAYERS * 64 * 4);
    float* pooled = (float*)alloc((size_t)NGRAPHS * HD * 4);

    k_encoder<<<(N_NODES * 8 + 255) / 256, 256, 0, stream>>>(x, W_enc, b_enc, hh,
                                                             stats, pooled);
    k_phist   <<<NPB, 256, 0, stream>>>(ei, pcnt);
    k_pscan   <<<1, 256, 0, stream>>>(pcnt, boff, offA);
    k_pscatter<<<NPB, 256, 0, stream>>>(ei, pcnt, ebuf);
    k_bfinal  <<<NBUCK, 512, 0, stream>>>(ebuf, boff, offA, csr);

    for (int l = 0; l < NLAYERS; ++l) {
        k_layer  <<<2048, 256, 0, stream>>>(hh, offA, csr, epsArr, W1, b1, W2, b2,
                                            z2, stats, l);
        k_bnapply<<<(N_NODES * HD / 4 + 255) / 256, 256, 0, stream>>>(z2, stats,
                                                                      gamma, beta,
                                                                      hh, l);
    }
    k_pool<<<(N_NODES + 255) / 256, 256, 0, stream>>>(hh, batch, pooled);
    k_cls <<<8, 256, 0, stream>>>(pooled, Wc, bc, out);
}

// Round 5
// 713.789 us; speedup vs baseline: 1.7686x; 1.7686x over previous
//
#include <hip/hip_runtime.h>

#define N_NODES 100000
#define N_EDGES 3200000
#define HD      32
#define NLAYERS 4
#define NGRAPHS 1000
#define BN_EPS  1e-5f
#define BSHIFT  9                         // 512-node buckets
#define NBUCK   ((N_NODES + 511) >> 9)    // 196
#define PCHUNK  8192                      // edges per partition block
#define NPB     ((N_EDGES + PCHUNK - 1) / PCHUNK)   // 391

typedef _Float16 f16;
typedef _Float16 f16x2 __attribute__((ext_vector_type(2)));
typedef _Float16 f16x4 __attribute__((ext_vector_type(4)));
typedef float    f32x2 __attribute__((ext_vector_type(2)));
typedef int      i32x4 __attribute__((ext_vector_type(4)));

__device__ __forceinline__ f32x2 ld2(const f16* p) {
    return __builtin_convertvector(*(const f16x2*)p, f32x2);
}

// ---------------- encoder: hh = f16(x*W_enc + b_enc)  (+ zero-init) -----------
__global__ __launch_bounds__(256) void k_encoder(
    const float* __restrict__ x, const float* __restrict__ W_enc,
    const float* __restrict__ b_enc, f16* __restrict__ hh,
    float* __restrict__ stats, float* __restrict__ pooled)
{
    int gid = blockIdx.x * 256 + threadIdx.x;        // over N*8 (4 ch each)
    if (gid < NLAYERS * 64)   stats[gid]  = 0.f;
    if (gid < NGRAPHS * HD)   pooled[gid] = 0.f;
    if (gid < N_NODES * 8) {
        int i = gid >> 3, c0 = (gid & 7) * 4;
        float xv = x[i];
        f16x4 r;
        #pragma unroll
        for (int k = 0; k < 4; ++k)
            r[k] = (f16)(xv * W_enc[c0 + k] + b_enc[c0 + k]);
        *(f16x4*)(hh + i * HD + c0) = r;
    }
}

// ---------------- deterministic radix partition (no global atomics) -----------
__global__ __launch_bounds__(256) void k_phist(const int* __restrict__ ei,
                                               int* __restrict__ pcnt)
{
    __shared__ int hist[256];
    int t = threadIdx.x, blk = blockIdx.x;
    hist[t] = 0;
    __syncthreads();
    int e0 = blk * PCHUNK, e1 = min(e0 + PCHUNK, N_EDGES);
    for (int e = e0 + t; e < e1; e += 256)
        atomicAdd(&hist[ei[N_EDGES + e] >> BSHIFT], 1);
    __syncthreads();
    pcnt[t * NPB + blk] = hist[t];
}

// per-bucket scan of the 391 per-block counts (in place -> exclusive prefixes)
__global__ __launch_bounds__(512) void k_pscanA(int* __restrict__ pcnt,
                                                int* __restrict__ btot)
{
    __shared__ int sc[2][512];
    int t = threadIdx.x, b = blockIdx.x;
    int base = b * NPB;
    int v = (t < NPB) ? pcnt[base + t] : 0;
    int pp = 0;
    sc[0][t] = v;
    __syncthreads();
    for (int st = 1; st < 512; st <<= 1) {
        int x = sc[pp][t];
        if (t >= st) x += sc[pp][t - st];
        sc[pp ^ 1][t] = x;
        pp ^= 1;
        __syncthreads();
    }
    int incl = sc[pp][t];
    if (t < NPB) pcnt[base + t] = incl - v;
    if (t == NPB - 1) btot[b] = incl;
}

// tiny scan over 196 bucket totals -> bucket bases
__global__ __launch_bounds__(256) void k_pscanB(const int* __restrict__ btot,
                                                int* __restrict__ boff,
                                                int* __restrict__ off)
{
    __shared__ int sc[2][256];
    int t = threadIdx.x;
    int v = (t < NBUCK) ? btot[t] : 0;
    int pp = 0;
    sc[0][t] = v;
    __syncthreads();
    for (int st = 1; st < 256; st <<= 1) {
        int x = sc[pp][t];
        if (t >= st) x += sc[pp][t - st];
        sc[pp ^ 1][t] = x;
        pp ^= 1;
        __syncthreads();
    }
    int incl = sc[pp][t];
    if (t < NBUCK) boff[t] = incl - v;
    if (t == NBUCK - 1) { boff[NBUCK] = incl; off[N_NODES] = incl; }
}

// scatter packed edges to exact positions (LDS cursors only)
__global__ __launch_bounds__(256) void k_pscatter(const int* __restrict__ ei,
                                                  const int* __restrict__ pcnt,
                                                  const int* __restrict__ boff,
                                                  unsigned int* __restrict__ ebuf)
{
    __shared__ int lcur[256];
    int t = threadIdx.x, blk = blockIdx.x;
    lcur[t] = pcnt[t * NPB + blk] + ((t < NBUCK) ? boff[t] : 0);
    __syncthreads();
    int e0 = blk * PCHUNK, e1 = min(e0 + PCHUNK, N_EDGES);
    for (int e = e0 + t; e < e1; e += 256) {
        int src = ei[e], dst = ei[N_EDGES + e];
        int b = dst >> BSHIFT;
        int pos = atomicAdd(&lcur[b], 1);            // LDS atomic: block-local
        ebuf[pos] = ((unsigned)src << BSHIFT) | (unsigned)(dst & 511);
    }
}

// per-bucket local sort -> final CSR + off[] (one block per bucket)
__global__ __launch_bounds__(512) void k_bfinal(const unsigned int* __restrict__ ebuf,
                                                const int* __restrict__ boff,
                                                int* __restrict__ off,
                                                int* __restrict__ csr)
{
    __shared__ int cnt[512], scanbuf[2][512], cur[512];
    int tid = threadIdx.x, b = blockIdx.x;
    int base = boff[b], nE = boff[b + 1] - base;
    cnt[tid] = 0;
    __syncthreads();
    for (int e = tid; e < nE; e += 512)
        atomicAdd(&cnt[ebuf[base + e] & 511], 1);
    __syncthreads();
    int pp = 0;
    scanbuf[0][tid] = cnt[tid];
    __syncthreads();
    for (int st = 1; st < 512; st <<= 1) {
        int v = scanbuf[pp][tid];
        if (tid >= st) v += scanbuf[pp][tid - st];
        scanbuf[pp ^ 1][tid] = v;
        pp ^= 1;
        __syncthreads();
    }
    int excl = scanbuf[pp][tid] - cnt[tid];
    cur[tid] = excl;
    int gnode = (b << BSHIFT) + tid;
    if (gnode < N_NODES) off[gnode] = base + excl;
    __syncthreads();
    for (int e = tid; e < nE; e += 512) {
        unsigned int p = ebuf[base + e];
        int pos = atomicAdd(&cur[p & 511], 1);
        csr[base + pos] = (int)(p >> BSHIFT);
    }
}

// ---------------- fused layer: (node, ch-pair) lanes, deep gather ILP ---------
// tid -> nb = tid>>4 (node in 16-group), li = tid&15, channels (2li, 2li+1).
// LDS MLP is wave-synchronous within each 16-lane group: no hot-loop barriers.
__global__ __launch_bounds__(256) void k_layer(
    const f16* __restrict__ hh, const int* __restrict__ off,
    const int* __restrict__ csr, const float* __restrict__ epsArr,
    const float* __restrict__ W1, const float* __restrict__ b1,
    const float* __restrict__ W2, const float* __restrict__ b2,
    f16* __restrict__ z2out, float* __restrict__ stats, int layer)
{
    __shared__ f32x2 W1s[512], W2s[512];             // [k][li] -> (W[k][2li],W[k][2li+1])
    __shared__ float z1s[16 * 33], ts[16 * 33];      // stride 33: conflict-free reads
    __shared__ float redS[4][32], redQ[4][32];
    int tid = threadIdx.x;
    const f32x2* W1l = (const f32x2*)(W1 + layer * 1024);
    const f32x2* W2l = (const f32x2*)(W2 + layer * 1024);
    for (int k = tid; k < 512; k += 256) { W1s[k] = W1l[k]; W2s[k] = W2l[k]; }
    int nb = tid >> 4, li = tid & 15, c0 = li * 2;
    f32x2 bias1 = { b1[layer * 32 + c0], b1[layer * 32 + c0 + 1] };
    f32x2 bias2 = { b2[layer * 32 + c0], b2[layer * 32 + c0 + 1] };
    float onePlusEps = 1.f + epsArr[layer];
    __syncthreads();

    f32x2 S = {0.f, 0.f}, Q = {0.f, 0.f};
    const int NGRP = N_NODES / 16;                   // 6250 exact
    for (int grp = blockIdx.x; grp < NGRP; grp += gridDim.x) {
        int node = grp * 16 + nb;
        int j = off[node], jend = off[node + 1];
        f32x2 A = {0.f,0.f}, B = {0.f,0.f}, C = {0.f,0.f}, D = {0.f,0.f};
        while (j < jend && (j & 3))                  // align to 16B
            A += ld2(hh + csr[j++] * HD + c0);
        int n8 = (jend - j) >> 3;
        for (int it = 0; it < n8; ++it) {            // 8 rows in flight / group
            i32x4 q0 = *(const i32x4*)(csr + j);
            i32x4 q1 = *(const i32x4*)(csr + j + 4);
            f16x2 g0 = *(const f16x2*)(hh + q0.x * HD + c0);
            f16x2 g1 = *(const f16x2*)(hh + q0.y * HD + c0);
            f16x2 g2 = *(const f16x2*)(hh + q0.z * HD + c0);
            f16x2 g3 = *(const f16x2*)(hh + q0.w * HD + c0);
            f16x2 g4 = *(const f16x2*)(hh + q1.x * HD + c0);
            f16x2 g5 = *(const f16x2*)(hh + q1.y * HD + c0);
            f16x2 g6 = *(const f16x2*)(hh + q1.z * HD + c0);
            f16x2 g7 = *(const f16x2*)(hh + q1.w * HD + c0);
            A += __builtin_convertvector(g0, f32x2);
            B += __builtin_convertvector(g1, f32x2);
            C += __builtin_convertvector(g2, f32x2);
            D += __builtin_convertvector(g3, f32x2);
            A += __builtin_convertvector(g4, f32x2);
            B += __builtin_convertvector(g5, f32x2);
            C += __builtin_convertvector(g6, f32x2);
            D += __builtin_convertvector(g7, f32x2);
            j += 8;
        }
        if (jend - j >= 4) {
            i32x4 q0 = *(const i32x4*)(csr + j);
            f16x2 g0 = *(const f16x2*)(hh + q0.x * HD + c0);
            f16x2 g1 = *(const f16x2*)(hh + q0.y * HD + c0);
            f16x2 g2 = *(const f16x2*)(hh + q0.z * HD + c0);
            f16x2 g3 = *(const f16x2*)(hh + q0.w * HD + c0);
            A += __builtin_convertvector(g0, f32x2);
            B += __builtin_convertvector(g1, f32x2);
            C += __builtin_convertvector(g2, f32x2);
            D += __builtin_convertvector(g3, f32x2);
            j += 4;
        }
        while (j < jend) A += ld2(hh + csr[j++] * HD + c0);

        f32x2 z1 = (A + B) + (C + D);
        z1 += onePlusEps * ld2(hh + node * HD + c0); // self term
        z1s[nb * 33 + c0]     = z1.x;                // wave-sync LDS (no barrier)
        z1s[nb * 33 + c0 + 1] = z1.y;

        f32x2 t = bias1;
        #pragma unroll
        for (int k = 0; k < 32; ++k) {
            float zk = z1s[nb * 33 + k];
            f32x2 w = W1s[k * 16 + li];
            t.x = fmaf(zk, w.x, t.x);
            t.y = fmaf(zk, w.y, t.y);
        }
        t.x = fmaxf(t.x, 0.f); t.y = fmaxf(t.y, 0.f);
        ts[nb * 33 + c0]     = t.x;
        ts[nb * 33 + c0 + 1] = t.y;

        f32x2 z2 = bias2;
        #pragma unroll
        for (int k = 0; k < 32; ++k) {
            float tk = ts[nb * 33 + k];
            f32x2 w = W2s[k * 16 + li];
            z2.x = fmaf(tk, w.x, z2.x);
            z2.y = fmaf(tk, w.y, z2.y);
        }
        *(f16x2*)(z2out + node * HD + c0) = __builtin_convertvector(z2, f16x2);
        S += z2;
        Q += z2 * z2;
    }

    // reduce over the 4 node-groups of each wave (lane bits 4,5)
    S.x += __shfl_xor(S.x, 16); S.y += __shfl_xor(S.y, 16);
    S.x += __shfl_xor(S.x, 32); S.y += __shfl_xor(S.y, 32);
    Q.x += __shfl_xor(Q.x, 16); Q.y += __shfl_xor(Q.y, 16);
    Q.x += __shfl_xor(Q.x, 32); Q.y += __shfl_xor(Q.y, 32);
    int lane = tid & 63, wave = tid >> 6;
    if (lane < 16) {
        redS[wave][c0] = S.x; redS[wave][c0 + 1] = S.y;
        redQ[wave][c0] = Q.x; redQ[wave][c0 + 1] = Q.y;
    }
    __syncthreads();
    if (tid < 64) {
        int sel = tid >> 5, cc = tid & 31;
        float s = 0.f;
        #pragma unroll
        for (int w = 0; w < 4; ++w) s += sel ? redQ[w][cc] : redS[w][cc];
        atomicAdd(&stats[layer * 64 + sel * 32 + cc], s);
    }
}

// ---------------- BatchNorm (batch stats) + ReLU -> hh -------------------------
__global__ __launch_bounds__(256) void k_bnapply(
    const f16* __restrict__ z2, const float* __restrict__ stats,
    const float* __restrict__ gamma, const float* __restrict__ beta,
    f16* __restrict__ hh, int layer)
{
    __shared__ float scs[32], shs[32];
    int t = threadIdx.x;
    if (t < 32) {
        const float invN = 1.0f / (float)N_NODES;
        float mu  = stats[layer * 64 + t] * invN;
        float var = stats[layer * 64 + 32 + t] * invN - mu * mu;
        float sc = gamma[layer * 32 + t] * rsqrtf(var + BN_EPS);
        scs[t] = sc;
        shs[t] = beta[layer * 32 + t] - mu * sc;
    }
    __syncthreads();
    int gid = blockIdx.x * 256 + t;                  // over N*HD/4
    if (gid >= N_NODES * HD / 4) return;
    int c0 = (gid * 4) & 31;
    f16x4 z = *(const f16x4*)(z2 + (size_t)gid * 4);
    f16x4 r;
    #pragma unroll
    for (int k = 0; k < 4; ++k)
        r[k] = (f16)fmaxf(fmaf((float)z[k], scs[c0 + k], shs[c0 + k]), 0.f);
    *(f16x4*)(hh + (size_t)gid * 4) = r;
}

// ---------------- global_add_pool (batch is sorted -> run-length reduce) -------
__global__ __launch_bounds__(256) void k_pool(const f16* __restrict__ hh,
                                              const int* __restrict__ batch,
                                              float* __restrict__ pooled)
{
    int c = threadIdx.x & 31, slot = threadIdx.x >> 5;
    int start = blockIdx.x * 256 + slot * 32;
    if (start >= N_NODES) return;
    int end = min(start + 32, N_NODES);
    int cur = batch[start]; float acc = 0.f;
    for (int i = start; i < end; ++i) {
        int g = batch[i];
        if (g != cur) { atomicAdd(&pooled[cur * HD + c], acc); acc = 0.f; cur = g; }
        acc += (float)hh[i * HD + c];
    }
    atomicAdd(&pooled[cur * HD + c], acc);
}

// ---------------- classifier ---------------------------------------------------
__global__ __launch_bounds__(256) void k_cls(const float* __restrict__ pooled,
                                             const float* __restrict__ Wc,
                                             const float* __restrict__ bc,
                                             float* __restrict__ out)
{
    int gid = blockIdx.x * 256 + threadIdx.x;
    if (gid >= NGRAPHS * 2) return;
    int g = gid >> 1, c = gid & 1;
    float s = bc[c];
    #pragma unroll
    for (int k = 0; k < 32; ++k) s = fmaf(pooled[g * 32 + k], Wc[k * 2 + c], s);
    out[gid] = s;
}

extern "C" void kernel_launch(void* const* d_in, const int* in_sizes, int n_in,
                              void* d_out, int out_size, void* d_ws, size_t ws_size,
                              hipStream_t stream)
{
    const float* x      = (const float*)d_in[0];
    const int*   ei     = (const int*)d_in[1];
    const int*   batch  = (const int*)d_in[2];
    const float* W_enc  = (const float*)d_in[3];
    const float* b_enc  = (const float*)d_in[4];
    const float* epsArr = (const float*)d_in[5];
    const float* W1     = (const float*)d_in[6];
    const float* b1     = (const float*)d_in[7];
    const float* W2     = (const float*)d_in[8];
    const float* b2     = (const float*)d_in[9];
    const float* gamma  = (const float*)d_in[10];
    const float* beta   = (const float*)d_in[11];
    const float* Wc     = (const float*)d_in[12];
    const float* bc     = (const float*)d_in[13];
    float* out = (float*)d_out;

    char* ws = (char*)d_ws;
    size_t o = 0;
    auto alloc = [&](size_t bytes) {
        char* p = ws + o;
        o += (bytes + 255) & ~(size_t)255;
        return p;
    };
    f16*   hh     = (f16*) alloc((size_t)N_NODES * HD * 2);    // 6.4 MB
    f16*   z2     = (f16*) alloc((size_t)N_NODES * HD * 2);    // 6.4 MB
    int*   csr    = (int*) alloc((size_t)N_EDGES * 4);         // 12.8 MB
    unsigned int* ebuf = (unsigned int*)alloc((size_t)N_EDGES * 4);  // 12.8 MB
    int*   offA   = (int*) alloc((size_t)(N_NODES + 1) * 4);
    int*   pcnt   = (int*) alloc((size_t)256 * NPB * 4);       // 0.4 MB
    int*   btot   = (int*) alloc(1024);
    int*   boff   = (int*) alloc(1024);
    float* stats  = (float*)alloc(NLAYERS * 64 * 4);
    float* pooled = (float*)alloc((size_t)NGRAPHS * HD * 4);

    k_encoder<<<(N_NODES * 8 + 255) / 256, 256, 0, stream>>>(x, W_enc, b_enc, hh,
                                                             stats, pooled);
    k_phist   <<<NPB, 256, 0, stream>>>(ei, pcnt);
    k_pscanA  <<<NBUCK, 512, 0, stream>>>(pcnt, btot);
    k_pscanB  <<<1, 256, 0, stream>>>(btot, boff, offA);
    k_pscatter<<<NPB, 256, 0, stream>>>(ei, pcnt, boff, ebuf);
    k_bfinal  <<<NBUCK, 512, 0, stream>>>(ebuf, boff, offA, csr);

    for (int l = 0; l < NLAYERS; ++l) {
        k_layer  <<<1563, 256, 0, stream>>>(hh, offA, csr, epsArr, W1, b1, W2, b2,
                                            z2, stats, l);
        k_bnapply<<<(N_NODES * HD / 4 + 255) / 256, 256, 0, stream>>>(z2, stats,
                                                                      gamma, beta,
                                                                      hh, l);
    }
    k_pool<<<(N_NODES + 255) / 256, 256, 0, stream>>>(hh, batch, pooled);
    k_cls <<<8, 256, 0, stream>>>(pooled, Wc, bc, out);
}

// Round 6
// 676.175 us; speedup vs baseline: 1.8670x; 1.0556x over previous
//
#include <hip/hip_runtime.h>

#define N_NODES 100000
#define N_EDGES 3200000
#define HD      32
#define NLAYERS 4
#define NGRAPHS 1000
#define BN_EPS  1e-5f
#define BSHIFT  9                         // 512-node buckets
#define NBUCK   ((N_NODES + 511) >> 9)    // 196
#define PCHUNK  8192                      // edges per partition block
#define NPB     ((N_EDGES + PCHUNK - 1) / PCHUNK)   // 391
#define PLANE   (N_NODES * 16)            // f16 elems per 16-channel plane

typedef _Float16 f16;
typedef _Float16 f16x2 __attribute__((ext_vector_type(2)));
typedef _Float16 f16x4 __attribute__((ext_vector_type(4)));
typedef float    f32x2 __attribute__((ext_vector_type(2)));
typedef int      i32x4 __attribute__((ext_vector_type(4)));

__device__ __forceinline__ f32x2 ld2(const f16* p) {
    return __builtin_convertvector(*(const f16x2*)p, f32x2);
}
__device__ __forceinline__ f32x2 ld2nt(const f16* p) {
    f16x2 v = __builtin_nontemporal_load((const f16x2*)p);
    return __builtin_convertvector(v, f32x2);
}
__device__ __forceinline__ void st2nt(f16* p, f32x2 v) {
    f16x2 r = __builtin_convertvector(v, f16x2);
    __builtin_nontemporal_store(r, (f16x2*)p);
}

// ---------------- encoder: hh(planes) = f16(x*W_enc + b_enc) (+ zero-init) ----
__global__ __launch_bounds__(256) void k_encoder(
    const float* __restrict__ x, const float* __restrict__ W_enc,
    const float* __restrict__ b_enc, f16* __restrict__ hh,
    float* __restrict__ stats, float* __restrict__ pooled)
{
    int gid = blockIdx.x * 256 + threadIdx.x;        // over N*8 (4 ch each)
    if (gid < NLAYERS * 64)   stats[gid]  = 0.f;
    if (gid < NGRAPHS * HD)   pooled[gid] = 0.f;
    if (gid < N_NODES * 8) {
        int i = gid >> 3, c0 = (gid & 7) * 4;
        float xv = x[i];
        f16x4 r;
        #pragma unroll
        for (int k = 0; k < 4; ++k)
            r[k] = (f16)(xv * W_enc[c0 + k] + b_enc[c0 + k]);
        int p = c0 >> 4, lc = c0 & 15;
        *(f16x4*)(hh + p * PLANE + i * 16 + lc) = r;
    }
}

// ---------------- deterministic radix partition (no global atomics) -----------
__global__ __launch_bounds__(256) void k_phist(const int* __restrict__ ei,
                                               int* __restrict__ pcnt)
{
    __shared__ int hist[256];
    int t = threadIdx.x, blk = blockIdx.x;
    hist[t] = 0;
    __syncthreads();
    int base4 = blk * (PCHUNK / 4);
    int n4 = min(PCHUNK / 4, N_EDGES / 4 - base4);
    const i32x4* d4 = (const i32x4*)(ei + N_EDGES);
    for (int k = t; k < n4; k += 256) {
        i32x4 d = __builtin_nontemporal_load(d4 + base4 + k);
        atomicAdd(&hist[d.x >> BSHIFT], 1);
        atomicAdd(&hist[d.y >> BSHIFT], 1);
        atomicAdd(&hist[d.z >> BSHIFT], 1);
        atomicAdd(&hist[d.w >> BSHIFT], 1);
    }
    __syncthreads();
    pcnt[t * NPB + blk] = hist[t];
}

// per-bucket scan of the per-block counts (in place -> exclusive prefixes)
__global__ __launch_bounds__(512) void k_pscanA(int* __restrict__ pcnt,
                                                int* __restrict__ btot)
{
    __shared__ int sc[2][512];
    int t = threadIdx.x, b = blockIdx.x;
    int base = b * NPB;
    int v = (t < NPB) ? pcnt[base + t] : 0;
    int pp = 0;
    sc[0][t] = v;
    __syncthreads();
    for (int st = 1; st < 512; st <<= 1) {
        int x = sc[pp][t];
        if (t >= st) x += sc[pp][t - st];
        sc[pp ^ 1][t] = x;
        pp ^= 1;
        __syncthreads();
    }
    int incl = sc[pp][t];
    if (t < NPB) pcnt[base + t] = incl - v;
    if (t == NPB - 1) btot[b] = incl;
}

// tiny scan over bucket totals -> bucket bases
__global__ __launch_bounds__(256) void k_pscanB(const int* __restrict__ btot,
                                                int* __restrict__ boff,
                                                int* __restrict__ off)
{
    __shared__ int sc[2][256];
    int t = threadIdx.x;
    int v = (t < NBUCK) ? btot[t] : 0;
    int pp = 0;
    sc[0][t] = v;
    __syncthreads();
    for (int st = 1; st < 256; st <<= 1) {
        int x = sc[pp][t];
        if (t >= st) x += sc[pp][t - st];
        sc[pp ^ 1][t] = x;
        pp ^= 1;
        __syncthreads();
    }
    int incl = sc[pp][t];
    if (t < NBUCK) boff[t] = incl - v;
    if (t == NBUCK - 1) { boff[NBUCK] = incl; off[N_NODES] = incl; }
}

// scatter packed edges to exact positions (LDS cursors only)
__global__ __launch_bounds__(256) void k_pscatter(const int* __restrict__ ei,
                                                  const int* __restrict__ pcnt,
                                                  const int* __restrict__ boff,
                                                  unsigned int* __restrict__ ebuf)
{
    __shared__ int lcur[256];
    int t = threadIdx.x, blk = blockIdx.x;
    lcur[t] = pcnt[t * NPB + blk] + ((t < NBUCK) ? boff[t] : 0);
    __syncthreads();
    int base4 = blk * (PCHUNK / 4);
    int n4 = min(PCHUNK / 4, N_EDGES / 4 - base4);
    const i32x4* s4 = (const i32x4*)ei;
    const i32x4* d4 = (const i32x4*)(ei + N_EDGES);
    for (int k = t; k < n4; k += 256) {
        i32x4 s = __builtin_nontemporal_load(s4 + base4 + k);
        i32x4 d = __builtin_nontemporal_load(d4 + base4 + k);
        int pos;
        pos = atomicAdd(&lcur[d.x >> BSHIFT], 1);
        ebuf[pos] = ((unsigned)s.x << BSHIFT) | (unsigned)(d.x & 511);
        pos = atomicAdd(&lcur[d.y >> BSHIFT], 1);
        ebuf[pos] = ((unsigned)s.y << BSHIFT) | (unsigned)(d.y & 511);
        pos = atomicAdd(&lcur[d.z >> BSHIFT], 1);
        ebuf[pos] = ((unsigned)s.z << BSHIFT) | (unsigned)(d.z & 511);
        pos = atomicAdd(&lcur[d.w >> BSHIFT], 1);
        ebuf[pos] = ((unsigned)s.w << BSHIFT) | (unsigned)(d.w & 511);
    }
}

// per-bucket local sort -> final CSR + off[] (one block per bucket)
__global__ __launch_bounds__(512) void k_bfinal(const unsigned int* __restrict__ ebuf,
                                                const int* __restrict__ boff,
                                                int* __restrict__ off,
                                                int* __restrict__ csr)
{
    __shared__ int cnt[512], scanbuf[2][512], cur[512];
    int tid = threadIdx.x, b = blockIdx.x;
    int base = boff[b], nE = boff[b + 1] - base;
    cnt[tid] = 0;
    __syncthreads();
    for (int e = tid; e < nE; e += 512)
        atomicAdd(&cnt[ebuf[base + e] & 511], 1);
    __syncthreads();
    int pp = 0;
    scanbuf[0][tid] = cnt[tid];
    __syncthreads();
    for (int st = 1; st < 512; st <<= 1) {
        int v = scanbuf[pp][tid];
        if (tid >= st) v += scanbuf[pp][tid - st];
        scanbuf[pp ^ 1][tid] = v;
        pp ^= 1;
        __syncthreads();
    }
    int excl = scanbuf[pp][tid] - cnt[tid];
    cur[tid] = excl;
    int gnode = (b << BSHIFT) + tid;
    if (gnode < N_NODES) off[gnode] = base + excl;
    __syncthreads();
    for (int e = tid; e < nE; e += 512) {
        unsigned int p = ebuf[base + e];
        int pos = atomicAdd(&cur[p & 511], 1);
        csr[base + pos] = (int)(p >> BSHIFT);
    }
}

// ---------------- plane-0 aggregation: z1lo = (1+eps)h0 + sum_nb h0 ----------
// 8 lanes per node (2 ch each); 32 nodes per block per group.
__global__ __launch_bounds__(256) void k_agg(
    const f16* __restrict__ hh, const int* __restrict__ off,
    const int* __restrict__ csr, const float* __restrict__ epsArr,
    f16* __restrict__ z1lo, int layer)
{
    int tid = threadIdx.x;
    int unit = tid >> 3, li = tid & 7, c0 = li * 2;
    float onePlusEps = 1.f + epsArr[layer];
    int node = blockIdx.x * 32 + unit;               // grid = N/32 blocks exact
    int j = off[node], jend = off[node + 1];
    f32x2 A = {0.f,0.f}, B = {0.f,0.f}, C = {0.f,0.f}, D = {0.f,0.f};
    while (j < jend && (j & 3)) A += ld2(hh + csr[j++] * 16 + c0);
    int n8 = (jend - j) >> 3;
    for (int it = 0; it < n8; ++it) {
        i32x4 q0 = __builtin_nontemporal_load((const i32x4*)(csr + j));
        i32x4 q1 = __builtin_nontemporal_load((const i32x4*)(csr + j + 4));
        f16x2 g0 = *(const f16x2*)(hh + q0.x * 16 + c0);
        f16x2 g1 = *(const f16x2*)(hh + q0.y * 16 + c0);
        f16x2 g2 = *(const f16x2*)(hh + q0.z * 16 + c0);
        f16x2 g3 = *(const f16x2*)(hh + q0.w * 16 + c0);
        f16x2 g4 = *(const f16x2*)(hh + q1.x * 16 + c0);
        f16x2 g5 = *(const f16x2*)(hh + q1.y * 16 + c0);
        f16x2 g6 = *(const f16x2*)(hh + q1.z * 16 + c0);
        f16x2 g7 = *(const f16x2*)(hh + q1.w * 16 + c0);
        A += __builtin_convertvector(g0, f32x2);
        B += __builtin_convertvector(g1, f32x2);
        C += __builtin_convertvector(g2, f32x2);
        D += __builtin_convertvector(g3, f32x2);
        A += __builtin_convertvector(g4, f32x2);
        B += __builtin_convertvector(g5, f32x2);
        C += __builtin_convertvector(g6, f32x2);
        D += __builtin_convertvector(g7, f32x2);
        j += 8;
    }
    if (jend - j >= 4) {
        i32x4 q0 = *(const i32x4*)(csr + j);
        A += ld2(hh + q0.x * 16 + c0);
        B += ld2(hh + q0.y * 16 + c0);
        C += ld2(hh + q0.z * 16 + c0);
        D += ld2(hh + q0.w * 16 + c0);
        j += 4;
    }
    while (j < jend) A += ld2(hh + csr[j++] * 16 + c0);
    f32x2 z1 = (A + B) + (C + D);
    z1 += onePlusEps * ld2(hh + node * 16 + c0);
    st2nt(z1lo + node * 16 + c0, z1);
}

// ---------------- fused: plane-1 aggregation + MLP + stats --------------------
// Per wave: 8 nodes. Phase A: 8-lane units gather plane1, pull z1lo -> LDS.
// Phase B: 16-lane units run the MLP (2 sub-iters of 4 nodes). Wave-sync LDS.
__global__ __launch_bounds__(256) void k_fused(
    const f16* __restrict__ hh, const int* __restrict__ off,
    const int* __restrict__ csr, const float* __restrict__ epsArr,
    const float* __restrict__ W1, const float* __restrict__ b1,
    const float* __restrict__ W2, const float* __restrict__ b2,
    const f16* __restrict__ z1lo, f16* __restrict__ z2out,
    float* __restrict__ stats, int layer)
{
    __shared__ f32x2 W1s[512], W2s[512];             // [k][li16]
    __shared__ float z1s[4][8][34];                  // [wave][node][ch]
    __shared__ float tss[4][4][33];                  // [wave][nsel][ch]
    __shared__ float redS[4][32], redQ[4][32];
    int tid = threadIdx.x, wave = tid >> 6, lane = tid & 63;
    const f32x2* W1l = (const f32x2*)(W1 + layer * 1024);
    const f32x2* W2l = (const f32x2*)(W2 + layer * 1024);
    for (int k = tid; k < 512; k += 256) { W1s[k] = W1l[k]; W2s[k] = W2l[k]; }
    int unit = lane >> 3, li8 = lane & 7;            // phase-A mapping
    int li16 = lane & 15, nsel = lane >> 4, c0 = li16 * 2;  // phase-B mapping
    f32x2 bias1 = { b1[layer * 32 + c0], b1[layer * 32 + c0 + 1] };
    f32x2 bias2 = { b2[layer * 32 + c0], b2[layer * 32 + c0 + 1] };
    float onePlusEps = 1.f + epsArr[layer];
    __syncthreads();

    const f16* hh1 = hh + PLANE;
    f32x2 S = {0.f,0.f}, Q = {0.f,0.f};
    const int NGRP = N_NODES / 32;                   // 3125
    for (int grp = blockIdx.x; grp < NGRP; grp += gridDim.x) {
        int node = grp * 32 + wave * 8 + unit;
        int ch = li8 * 2;                            // local ch in plane1
        int j = off[node], jend = off[node + 1];
        f32x2 A = {0.f,0.f}, B = {0.f,0.f}, C = {0.f,0.f}, D = {0.f,0.f};
        while (j < jend && (j & 3)) A += ld2(hh1 + csr[j++] * 16 + ch);
        int n8 = (jend - j) >> 3;
        for (int it = 0; it < n8; ++it) {
            i32x4 q0 = __builtin_nontemporal_load((const i32x4*)(csr + j));
            i32x4 q1 = __builtin_nontemporal_load((const i32x4*)(csr + j + 4));
            f16x2 g0 = *(const f16x2*)(hh1 + q0.x * 16 + ch);
            f16x2 g1 = *(const f16x2*)(hh1 + q0.y * 16 + ch);
            f16x2 g2 = *(const f16x2*)(hh1 + q0.z * 16 + ch);
            f16x2 g3 = *(const f16x2*)(hh1 + q0.w * 16 + ch);
            f16x2 g4 = *(const f16x2*)(hh1 + q1.x * 16 + ch);
            f16x2 g5 = *(const f16x2*)(hh1 + q1.y * 16 + ch);
            f16x2 g6 = *(const f16x2*)(hh1 + q1.z * 16 + ch);
            f16x2 g7 = *(const f16x2*)(hh1 + q1.w * 16 + ch);
            A += __builtin_convertvector(g0, f32x2);
            B += __builtin_convertvector(g1, f32x2);
            C += __builtin_convertvector(g2, f32x2);
            D += __builtin_convertvector(g3, f32x2);
            A += __builtin_convertvector(g4, f32x2);
            B += __builtin_convertvector(g5, f32x2);
            C += __builtin_convertvector(g6, f32x2);
            D += __builtin_convertvector(g7, f32x2);
            j += 8;
        }
        if (jend - j >= 4) {
            i32x4 q0 = *(const i32x4*)(csr + j);
            A += ld2(hh1 + q0.x * 16 + ch);
            B += ld2(hh1 + q0.y * 16 + ch);
            C += ld2(hh1 + q0.z * 16 + ch);
            D += ld2(hh1 + q0.w * 16 + ch);
            j += 4;
        }
        while (j < jend) A += ld2(hh1 + csr[j++] * 16 + ch);
        f32x2 z1h = (A + B) + (C + D);
        z1h += onePlusEps * ld2(hh1 + node * 16 + ch);
        z1s[wave][unit][16 + ch]     = z1h.x;        // wave-sync LDS, no barrier
        z1s[wave][unit][16 + ch + 1] = z1h.y;
        f32x2 zlo = ld2nt(z1lo + node * 16 + ch);    // stream plane-0 z1 back
        z1s[wave][unit][ch]     = zlo.x;
        z1s[wave][unit][ch + 1] = zlo.y;

        #pragma unroll
        for (int s = 0; s < 2; ++s) {                // MLP over 8 nodes, 4 at a time
            int nm = s * 4 + nsel;
            int nodeM = grp * 32 + wave * 8 + nm;
            f32x2 t = bias1;
            #pragma unroll
            for (int k = 0; k < 32; ++k) {
                float zk = z1s[wave][nm][k];
                f32x2 w = W1s[k * 16 + li16];
                t.x = fmaf(zk, w.x, t.x);
                t.y = fmaf(zk, w.y, t.y);
            }
            t.x = fmaxf(t.x, 0.f); t.y = fmaxf(t.y, 0.f);
            tss[wave][nsel][c0]     = t.x;
            tss[wave][nsel][c0 + 1] = t.y;
            f32x2 z2 = bias2;
            #pragma unroll
            for (int k = 0; k < 32; ++k) {
                float tk = tss[wave][nsel][k];
                f32x2 w = W2s[k * 16 + li16];
                z2.x = fmaf(tk, w.x, z2.x);
                z2.y = fmaf(tk, w.y, z2.y);
            }
            int p = c0 >> 4, lc = c0 & 15;
            st2nt(z2out + p * PLANE + nodeM * 16 + lc, z2);
            S += z2;
            Q += z2 * z2;
        }
    }

    S.x += __shfl_xor(S.x, 16); S.y += __shfl_xor(S.y, 16);
    S.x += __shfl_xor(S.x, 32); S.y += __shfl_xor(S.y, 32);
    Q.x += __shfl_xor(Q.x, 16); Q.y += __shfl_xor(Q.y, 16);
    Q.x += __shfl_xor(Q.x, 32); Q.y += __shfl_xor(Q.y, 32);
    if (lane < 16) {
        redS[wave][c0] = S.x; redS[wave][c0 + 1] = S.y;
        redQ[wave][c0] = Q.x; redQ[wave][c0 + 1] = Q.y;
    }
    __syncthreads();
    if (tid < 64) {
        int sel = tid >> 5, cc = tid & 31;
        float s = 0.f;
        #pragma unroll
        for (int w = 0; w < 4; ++w) s += sel ? redQ[w][cc] : redS[w][cc];
        atomicAdd(&stats[layer * 64 + sel * 32 + cc], s);
    }
}

// ---------------- BatchNorm (batch stats) + ReLU -> hh (plane layout) ---------
__global__ __launch_bounds__(256) void k_bnapply(
    const f16* __restrict__ z2, const float* __restrict__ stats,
    const float* __restrict__ gamma, const float* __restrict__ beta,
    f16* __restrict__ hh, int layer)
{
    __shared__ float scs[32], shs[32];
    int t = threadIdx.x;
    if (t < 32) {
        const float invN = 1.0f / (float)N_NODES;
        float mu  = stats[layer * 64 + t] * invN;
        float var = stats[layer * 64 + 32 + t] * invN - mu * mu;
        float sc = gamma[layer * 32 + t] * rsqrtf(var + BN_EPS);
        scs[t] = sc;
        shs[t] = beta[layer * 32 + t] - mu * sc;
    }
    __syncthreads();
    int gid = blockIdx.x * 256 + t;                  // over 2*PLANE/4 chunks
    if (gid >= 2 * PLANE / 4) return;
    int fid = gid * 4;
    int p = fid >= PLANE;
    int lc = fid & 15;                               // aligned 4
    int cb = p * 16 + lc;
    f16x4 z = __builtin_nontemporal_load((const f16x4*)(z2 + fid));
    f16x4 r;
    #pragma unroll
    for (int k = 0; k < 4; ++k)
        r[k] = (f16)fmaxf(fmaf((float)z[k], scs[cb + k], shs[cb + k]), 0.f);
    *(f16x4*)(hh + fid) = r;
}

// ---------------- global_add_pool (batch is sorted -> run-length reduce) ------
__global__ __launch_bounds__(256) void k_pool(const f16* __restrict__ hh,
                                              const int* __restrict__ batch,
                                              float* __restrict__ pooled)
{
    int c = threadIdx.x & 31, slot = threadIdx.x >> 5;
    const f16* hp = hh + (c >> 4) * PLANE;
    int lc = c & 15;
    int start = blockIdx.x * 256 + slot * 32;
    if (start >= N_NODES) return;
    int end = min(start + 32, N_NODES);
    int cur = batch[start]; float acc = 0.f;
    for (int i = start; i < end; ++i) {
        int g = batch[i];
        if (g != cur) { atomicAdd(&pooled[cur * HD + c], acc); acc = 0.f; cur = g; }
        acc += (float)hp[i * 16 + lc];
    }
    atomicAdd(&pooled[cur * HD + c], acc);
}

// ---------------- classifier ---------------------------------------------------
__global__ __launch_bounds__(256) void k_cls(const float* __restrict__ pooled,
                                             const float* __restrict__ Wc,
                                             const float* __restrict__ bc,
                                             float* __restrict__ out)
{
    int gid = blockIdx.x * 256 + threadIdx.x;
    if (gid >= NGRAPHS * 2) return;
    int g = gid >> 1, c = gid & 1;
    float s = bc[c];
    #pragma unroll
    for (int k = 0; k < 32; ++k) s = fmaf(pooled[g * 32 + k], Wc[k * 2 + c], s);
    out[gid] = s;
}

extern "C" void kernel_launch(void* const* d_in, const int* in_sizes, int n_in,
                              void* d_out, int out_size, void* d_ws, size_t ws_size,
                              hipStream_t stream)
{
    const float* x      = (const float*)d_in[0];
    const int*   ei     = (const int*)d_in[1];
    const int*   batch  = (const int*)d_in[2];
    const float* W_enc  = (const float*)d_in[3];
    const float* b_enc  = (const float*)d_in[4];
    const float* epsArr = (const float*)d_in[5];
    const float* W1     = (const float*)d_in[6];
    const float* b1     = (const float*)d_in[7];
    const float* W2     = (const float*)d_in[8];
    const float* b2     = (const float*)d_in[9];
    const float* gamma  = (const float*)d_in[10];
    const float* beta   = (const float*)d_in[11];
    const float* Wc     = (const float*)d_in[12];
    const float* bc     = (const float*)d_in[13];
    float* out = (float*)d_out;

    char* ws = (char*)d_ws;
    size_t o = 0;
    auto alloc = [&](size_t bytes) {
        char* p = ws + o;
        o += (bytes + 255) & ~(size_t)255;
        return p;
    };
    f16*   hh     = (f16*) alloc((size_t)2 * PLANE * 2);       // 6.4 MB (2 planes)
    f16*   z2     = (f16*) alloc((size_t)2 * PLANE * 2);       // 6.4 MB
    f16*   z1lo   = (f16*) alloc((size_t)PLANE * 2);           // 3.2 MB
    int*   csr    = (int*) alloc((size_t)N_EDGES * 4);         // 12.8 MB
    unsigned int* ebuf = (unsigned int*)alloc((size_t)N_EDGES * 4);  // 12.8 MB
    int*   offA   = (int*) alloc((size_t)(N_NODES + 1) * 4);
    int*   pcnt   = (int*) alloc((size_t)256 * NPB * 4);       // 0.4 MB
    int*   btot   = (int*) alloc(1024);
    int*   boff   = (int*) alloc(1024);
    float* stats  = (float*)alloc(NLAYERS * 64 * 4);
    float* pooled = (float*)alloc((size_t)NGRAPHS * HD * 4);

    k_encoder<<<(N_NODES * 8 + 255) / 256, 256, 0, stream>>>(x, W_enc, b_enc, hh,
                                                             stats, pooled);
    k_phist   <<<NPB, 256, 0, stream>>>(ei, pcnt);
    k_pscanA  <<<NBUCK, 512, 0, stream>>>(pcnt, btot);
    k_pscanB  <<<1, 256, 0, stream>>>(btot, boff, offA);
    k_pscatter<<<NPB, 256, 0, stream>>>(ei, pcnt, boff, ebuf);
    k_bfinal  <<<NBUCK, 512, 0, stream>>>(ebuf, boff, offA, csr);

    for (int l = 0; l < NLAYERS; ++l) {
        k_agg    <<<N_NODES / 32, 256, 0, stream>>>(hh, offA, csr, epsArr,
                                                    z1lo, l);
        k_fused  <<<1042, 256, 0, stream>>>(hh, offA, csr, epsArr, W1, b1, W2, b2,
                                            z1lo, z2, stats, l);
        k_bnapply<<<(2 * PLANE / 4 + 255) / 256, 256, 0, stream>>>(z2, stats,
                                                                   gamma, beta,
                                                                   hh, l);
    }
    k_pool<<<(N_NODES + 255) / 256, 256, 0, stream>>>(hh, batch, pooled);
    k_cls <<<8, 256, 0, stream>>>(pooled, Wc, bc, out);
}

// Round 7
// 665.154 us; speedup vs baseline: 1.8979x; 1.0166x over previous
//
#include <hip/hip_runtime.h>

#define N_NODES 100000
#define N_EDGES 3200000
#define HD      32
#define NLAYERS 4
#define NGRAPHS 1000
#define BN_EPS  1e-5f
#define BSHIFT  9                         // 512-node buckets
#define NBUCK   ((N_NODES + 511) >> 9)    // 196
#define PCHUNK  8192                      // edges per partition block
#define NPB     ((N_EDGES + PCHUNK - 1) / PCHUNK)   // 391
#define PLANE   (N_NODES * 16)            // f16 elems per 16-channel plane

typedef _Float16 f16;
typedef _Float16 f16x2 __attribute__((ext_vector_type(2)));
typedef _Float16 f16x4 __attribute__((ext_vector_type(4)));
typedef float    f32x2 __attribute__((ext_vector_type(2)));
typedef float    f32x4 __attribute__((ext_vector_type(4)));
typedef int      i32x4 __attribute__((ext_vector_type(4)));

__device__ __forceinline__ f32x2 ld2(const f16* p) {
    return __builtin_convertvector(*(const f16x2*)p, f32x2);
}
__device__ __forceinline__ f32x4 ld4cv(const f16* p) {
    return __builtin_convertvector(*(const f16x4*)p, f32x4);
}
__device__ __forceinline__ f32x4 cv4(f16x4 v) {
    return __builtin_convertvector(v, f32x4);
}
__device__ __forceinline__ void st2nt(f16* p, f32x2 v) {
    f16x2 r = __builtin_convertvector(v, f16x2);
    __builtin_nontemporal_store(r, (f16x2*)p);
}
__device__ __forceinline__ void st4nt(f16* p, f32x4 v) {
    f16x4 r = __builtin_convertvector(v, f16x4);
    __builtin_nontemporal_store(r, (f16x4*)p);
}

// ---------------- encoder: hh(planes) = f16(x*W_enc + b_enc) (+ zero-init) ----
__global__ __launch_bounds__(256) void k_encoder(
    const float* __restrict__ x, const float* __restrict__ W_enc,
    const float* __restrict__ b_enc, f16* __restrict__ hh,
    float* __restrict__ stats, float* __restrict__ pooled)
{
    int gid = blockIdx.x * 256 + threadIdx.x;        // over N*8 (4 ch each)
    if (gid < NLAYERS * 64)   stats[gid]  = 0.f;
    if (gid < NGRAPHS * HD)   pooled[gid] = 0.f;
    if (gid < N_NODES * 8) {
        int i = gid >> 3, c0 = (gid & 7) * 4;
        float xv = x[i];
        f16x4 r;
        #pragma unroll
        for (int k = 0; k < 4; ++k)
            r[k] = (f16)(xv * W_enc[c0 + k] + b_enc[c0 + k]);
        int p = c0 >> 4, lc = c0 & 15;
        *(f16x4*)(hh + p * PLANE + i * 16 + lc) = r;
    }
}

// ---------------- deterministic radix partition (no global atomics) -----------
__global__ __launch_bounds__(256) void k_phist(const int* __restrict__ ei,
                                               int* __restrict__ pcnt)
{
    __shared__ int hist[256];
    int t = threadIdx.x, blk = blockIdx.x;
    hist[t] = 0;
    __syncthreads();
    int base4 = blk * (PCHUNK / 4);
    int n4 = min(PCHUNK / 4, N_EDGES / 4 - base4);
    const i32x4* d4 = (const i32x4*)(ei + N_EDGES);
    for (int k = t; k < n4; k += 256) {
        i32x4 d = __builtin_nontemporal_load(d4 + base4 + k);
        atomicAdd(&hist[d.x >> BSHIFT], 1);
        atomicAdd(&hist[d.y >> BSHIFT], 1);
        atomicAdd(&hist[d.z >> BSHIFT], 1);
        atomicAdd(&hist[d.w >> BSHIFT], 1);
    }
    __syncthreads();
    pcnt[t * NPB + blk] = hist[t];
}

__global__ __launch_bounds__(512) void k_pscanA(int* __restrict__ pcnt,
                                                int* __restrict__ btot)
{
    __shared__ int sc[2][512];
    int t = threadIdx.x, b = blockIdx.x;
    int base = b * NPB;
    int v = (t < NPB) ? pcnt[base + t] : 0;
    int pp = 0;
    sc[0][t] = v;
    __syncthreads();
    for (int st = 1; st < 512; st <<= 1) {
        int x = sc[pp][t];
        if (t >= st) x += sc[pp][t - st];
        sc[pp ^ 1][t] = x;
        pp ^= 1;
        __syncthreads();
    }
    int incl = sc[pp][t];
    if (t < NPB) pcnt[base + t] = incl - v;
    if (t == NPB - 1) btot[b] = incl;
}

__global__ __launch_bounds__(256) void k_pscanB(const int* __restrict__ btot,
                                                int* __restrict__ boff,
                                                int* __restrict__ off)
{
    __shared__ int sc[2][256];
    int t = threadIdx.x;
    int v = (t < NBUCK) ? btot[t] : 0;
    int pp = 0;
    sc[0][t] = v;
    __syncthreads();
    for (int st = 1; st < 256; st <<= 1) {
        int x = sc[pp][t];
        if (t >= st) x += sc[pp][t - st];
        sc[pp ^ 1][t] = x;
        pp ^= 1;
        __syncthreads();
    }
    int incl = sc[pp][t];
    if (t < NBUCK) boff[t] = incl - v;
    if (t == NBUCK - 1) { boff[NBUCK] = incl; off[N_NODES] = incl; }
}

__global__ __launch_bounds__(256) void k_pscatter(const int* __restrict__ ei,
                                                  const int* __restrict__ pcnt,
                                                  const int* __restrict__ boff,
                                                  unsigned int* __restrict__ ebuf)
{
    __shared__ int lcur[256];
    int t = threadIdx.x, blk = blockIdx.x;
    lcur[t] = pcnt[t * NPB + blk] + ((t < NBUCK) ? boff[t] : 0);
    __syncthreads();
    int base4 = blk * (PCHUNK / 4);
    int n4 = min(PCHUNK / 4, N_EDGES / 4 - base4);
    const i32x4* s4 = (const i32x4*)ei;
    const i32x4* d4 = (const i32x4*)(ei + N_EDGES);
    for (int k = t; k < n4; k += 256) {
        i32x4 s = __builtin_nontemporal_load(s4 + base4 + k);
        i32x4 d = __builtin_nontemporal_load(d4 + base4 + k);
        int pos;
        pos = atomicAdd(&lcur[d.x >> BSHIFT], 1);
        ebuf[pos] = ((unsigned)s.x << BSHIFT) | (unsigned)(d.x & 511);
        pos = atomicAdd(&lcur[d.y >> BSHIFT], 1);
        ebuf[pos] = ((unsigned)s.y << BSHIFT) | (unsigned)(d.y & 511);
        pos = atomicAdd(&lcur[d.z >> BSHIFT], 1);
        ebuf[pos] = ((unsigned)s.z << BSHIFT) | (unsigned)(d.z & 511);
        pos = atomicAdd(&lcur[d.w >> BSHIFT], 1);
        ebuf[pos] = ((unsigned)s.w << BSHIFT) | (unsigned)(d.w & 511);
    }
}

__global__ __launch_bounds__(512) void k_bfinal(const unsigned int* __restrict__ ebuf,
                                                const int* __restrict__ boff,
                                                int* __restrict__ off,
                                                int* __restrict__ csr)
{
    __shared__ int cnt[512], scanbuf[2][512], cur[512];
    int tid = threadIdx.x, b = blockIdx.x;
    int base = boff[b], nE = boff[b + 1] - base;
    cnt[tid] = 0;
    __syncthreads();
    for (int e = tid; e < nE; e += 512)
        atomicAdd(&cnt[ebuf[base + e] & 511], 1);
    __syncthreads();
    int pp = 0;
    scanbuf[0][tid] = cnt[tid];
    __syncthreads();
    for (int st = 1; st < 512; st <<= 1) {
        int v = scanbuf[pp][tid];
        if (tid >= st) v += scanbuf[pp][tid - st];
        scanbuf[pp ^ 1][tid] = v;
        pp ^= 1;
        __syncthreads();
    }
    int excl = scanbuf[pp][tid] - cnt[tid];
    cur[tid] = excl;
    int gnode = (b << BSHIFT) + tid;
    if (gnode < N_NODES) off[gnode] = base + excl;
    __syncthreads();
    for (int e = tid; e < nE; e += 512) {
        unsigned int p = ebuf[base + e];
        int pos = atomicAdd(&cur[p & 511], 1);
        csr[base + pos] = (int)(p >> BSHIFT);
    }
}

// ---------------- plane aggregation with inline BN(prev)+ReLU ------------------
// 4 lanes/node (4 ch each, f16x4 loads). Wave = 16 nodes. No LDS, no barriers.
// z1_p[node] = (1+eps_l)*f(h_node) + sum_src f(h_src),  f = relu(sc*x+sh)
__global__ __launch_bounds__(256) void k_agg(
    const f16* __restrict__ hraw, const int* __restrict__ off,
    const int* __restrict__ csr, const float* __restrict__ epsArr,
    const float* __restrict__ stats, const float* __restrict__ gamma,
    const float* __restrict__ beta, f16* __restrict__ z1out,
    int layer, int plane)
{
    int tid = threadIdx.x;
    int unit = tid >> 2, li = tid & 3;
    int node = blockIdx.x * 64 + unit;
    if (node >= N_NODES) return;
    int cb = plane * 16 + li * 4;                    // first of 4 channels
    f32x4 sc, sh;
    bool relu = (layer > 0);
    if (relu) {
        const float invN = 1.0f / (float)N_NODES;
        #pragma unroll
        for (int k = 0; k < 4; ++k) {
            int ch = cb + k;
            float mu  = stats[(layer - 1) * 64 + ch] * invN;
            float var = stats[(layer - 1) * 64 + 32 + ch] * invN - mu * mu;
            float s = gamma[(layer - 1) * 32 + ch] * rsqrtf(var + BN_EPS);
            sc[k] = s;
            sh[k] = beta[(layer - 1) * 32 + ch] - mu * s;
        }
    } else {
        #pragma unroll
        for (int k = 0; k < 4; ++k) { sc[k] = 1.f; sh[k] = 0.f; }
    }
    float oneEps = 1.f + epsArr[layer];
    const f16* hp = hraw + plane * PLANE;
    int co = li * 4;

    auto bnf = [&](f32x4 v) -> f32x4 {
        f32x4 r;
        #pragma unroll
        for (int k = 0; k < 4; ++k) {
            r[k] = fmaf(v[k], sc[k], sh[k]);
            if (relu) r[k] = fmaxf(r[k], 0.f);
        }
        return r;
    };

    int j = off[node], jend = off[node + 1];
    f32x4 A = {0,0,0,0}, B = {0,0,0,0}, C = {0,0,0,0}, D = {0,0,0,0};
    while (j < jend && (j & 3)) A += bnf(ld4cv(hp + csr[j++] * 16 + co));
    int n8 = (jend - j) >> 3;
    for (int it = 0; it < n8; ++it) {
        i32x4 q0 = __builtin_nontemporal_load((const i32x4*)(csr + j));
        i32x4 q1 = __builtin_nontemporal_load((const i32x4*)(csr + j + 4));
        f16x4 g0 = *(const f16x4*)(hp + q0.x * 16 + co);
        f16x4 g1 = *(const f16x4*)(hp + q0.y * 16 + co);
        f16x4 g2 = *(const f16x4*)(hp + q0.z * 16 + co);
        f16x4 g3 = *(const f16x4*)(hp + q0.w * 16 + co);
        f16x4 g4 = *(const f16x4*)(hp + q1.x * 16 + co);
        f16x4 g5 = *(const f16x4*)(hp + q1.y * 16 + co);
        f16x4 g6 = *(const f16x4*)(hp + q1.z * 16 + co);
        f16x4 g7 = *(const f16x4*)(hp + q1.w * 16 + co);
        A += bnf(cv4(g0)); B += bnf(cv4(g1)); C += bnf(cv4(g2)); D += bnf(cv4(g3));
        A += bnf(cv4(g4)); B += bnf(cv4(g5)); C += bnf(cv4(g6)); D += bnf(cv4(g7));
        j += 8;
    }
    if (jend - j >= 4) {
        i32x4 q0 = *(const i32x4*)(csr + j);
        A += bnf(ld4cv(hp + q0.x * 16 + co));
        B += bnf(ld4cv(hp + q0.y * 16 + co));
        C += bnf(ld4cv(hp + q0.z * 16 + co));
        D += bnf(ld4cv(hp + q0.w * 16 + co));
        j += 4;
    }
    while (j < jend) A += bnf(ld4cv(hp + csr[j++] * 16 + co));

    f32x4 z1 = (A + B) + (C + D);
    z1 += oneEps * bnf(ld4cv(hp + node * 16 + co));
    st4nt(z1out + plane * PLANE + node * 16 + co, z1);
}

// ---------------- MLP (z1 -> z2 pre-BN) + stats --------------------------------
// 16 lanes/node (2 ch each), wave = 4 nodes. Wave-sync LDS, no hot barriers.
__global__ __launch_bounds__(256) void k_mlp(
    const f16* __restrict__ z1, const float* __restrict__ W1,
    const float* __restrict__ b1, const float* __restrict__ W2,
    const float* __restrict__ b2, f16* __restrict__ z2out,
    float* __restrict__ stats, int layer)
{
    __shared__ f32x2 W1s[512], W2s[512];             // [k][li16]
    __shared__ float z1s[4][4][34], tss[4][4][33];
    __shared__ float redS[4][32], redQ[4][32];
    int tid = threadIdx.x, wave = tid >> 6, lane = tid & 63;
    const f32x2* W1l = (const f32x2*)(W1 + layer * 1024);
    const f32x2* W2l = (const f32x2*)(W2 + layer * 1024);
    for (int k = tid; k < 512; k += 256) { W1s[k] = W1l[k]; W2s[k] = W2l[k]; }
    int li16 = lane & 15, nsel = lane >> 4, c0 = li16 * 2;
    int pl = c0 >> 4, lc = c0 & 15;
    f32x2 bias1 = { b1[layer * 32 + c0], b1[layer * 32 + c0 + 1] };
    f32x2 bias2 = { b2[layer * 32 + c0], b2[layer * 32 + c0 + 1] };
    __syncthreads();

    f32x2 S = {0.f,0.f}, Q = {0.f,0.f};
    const int NGRP = N_NODES / 16;                   // 6250 exact
    for (int grp = blockIdx.x; grp < NGRP; grp += gridDim.x) {
        int node = grp * 16 + wave * 4 + nsel;
        f32x2 z = ld2(z1 + pl * PLANE + node * 16 + lc);
        z1s[wave][nsel][c0]     = z.x;               // wave-sync LDS
        z1s[wave][nsel][c0 + 1] = z.y;

        f32x2 t = bias1;
        #pragma unroll
        for (int k = 0; k < 32; ++k) {
            float zk = z1s[wave][nsel][k];
            f32x2 w = W1s[k * 16 + li16];
            t.x = fmaf(zk, w.x, t.x);
            t.y = fmaf(zk, w.y, t.y);
        }
        t.x = fmaxf(t.x, 0.f); t.y = fmaxf(t.y, 0.f);
        tss[wave][nsel][c0]     = t.x;
        tss[wave][nsel][c0 + 1] = t.y;

        f32x2 z2 = bias2;
        #pragma unroll
        for (int k = 0; k < 32; ++k) {
            float tk = tss[wave][nsel][k];
            f32x2 w = W2s[k * 16 + li16];
            z2.x = fmaf(tk, w.x, z2.x);
            z2.y = fmaf(tk, w.y, z2.y);
        }
        st2nt(z2out + pl * PLANE + node * 16 + lc, z2);
        S += z2;
        Q += z2 * z2;
    }

    S.x += __shfl_xor(S.x, 16); S.y += __shfl_xor(S.y, 16);
    S.x += __shfl_xor(S.x, 32); S.y += __shfl_xor(S.y, 32);
    Q.x += __shfl_xor(Q.x, 16); Q.y += __shfl_xor(Q.y, 16);
    Q.x += __shfl_xor(Q.x, 32); Q.y += __shfl_xor(Q.y, 32);
    if (lane < 16) {
        redS[wave][c0] = S.x; redS[wave][c0 + 1] = S.y;
        redQ[wave][c0] = Q.x; redQ[wave][c0 + 1] = Q.y;
    }
    __syncthreads();
    if (tid < 64) {
        int sel = tid >> 5, cc = tid & 31;
        float s = 0.f;
        #pragma unroll
        for (int w = 0; w < 4; ++w) s += sel ? redQ[w][cc] : redS[w][cc];
        atomicAdd(&stats[layer * 64 + sel * 32 + cc], s);
    }
}

// ---------------- global_add_pool with inline BN(3)+ReLU -----------------------
__global__ __launch_bounds__(256) void k_pool(const f16* __restrict__ hraw,
                                              const int* __restrict__ batch,
                                              const float* __restrict__ stats,
                                              const float* __restrict__ gamma,
                                              const float* __restrict__ beta,
                                              float* __restrict__ pooled)
{
    int c = threadIdx.x & 31, slot = threadIdx.x >> 5;
    const float invN = 1.0f / (float)N_NODES;
    float mu  = stats[3 * 64 + c] * invN;
    float var = stats[3 * 64 + 32 + c] * invN - mu * mu;
    float sc = gamma[3 * 32 + c] * rsqrtf(var + BN_EPS);
    float sh = beta[3 * 32 + c] - mu * sc;
    const f16* hp = hraw + (c >> 4) * PLANE;
    int lc = c & 15;
    int start = blockIdx.x * 256 + slot * 32;
    if (start >= N_NODES) return;
    int end = min(start + 32, N_NODES);
    int cur = batch[start]; float acc = 0.f;
    for (int i = start; i < end; ++i) {
        int g = batch[i];
        if (g != cur) { atomicAdd(&pooled[cur * HD + c], acc); acc = 0.f; cur = g; }
        acc += fmaxf(fmaf((float)hp[i * 16 + lc], sc, sh), 0.f);
    }
    atomicAdd(&pooled[cur * HD + c], acc);
}

// ---------------- classifier ---------------------------------------------------
__global__ __launch_bounds__(256) void k_cls(const float* __restrict__ pooled,
                                             const float* __restrict__ Wc,
                                             const float* __restrict__ bc,
                                             float* __restrict__ out)
{
    int gid = blockIdx.x * 256 + threadIdx.x;
    if (gid >= NGRAPHS * 2) return;
    int g = gid >> 1, c = gid & 1;
    float s = bc[c];
    #pragma unroll
    for (int k = 0; k < 32; ++k) s = fmaf(pooled[g * 32 + k], Wc[k * 2 + c], s);
    out[gid] = s;
}

extern "C" void kernel_launch(void* const* d_in, const int* in_sizes, int n_in,
                              void* d_out, int out_size, void* d_ws, size_t ws_size,
                              hipStream_t stream)
{
    const float* x      = (const float*)d_in[0];
    const int*   ei     = (const int*)d_in[1];
    const int*   batch  = (const int*)d_in[2];
    const float* W_enc  = (const float*)d_in[3];
    const float* b_enc  = (const float*)d_in[4];
    const float* epsArr = (const float*)d_in[5];
    const float* W1     = (const float*)d_in[6];
    const float* b1     = (const float*)d_in[7];
    const float* W2     = (const float*)d_in[8];
    const float* b2     = (const float*)d_in[9];
    const float* gamma  = (const float*)d_in[10];
    const float* beta   = (const float*)d_in[11];
    const float* Wc     = (const float*)d_in[12];
    const float* bc     = (const float*)d_in[13];
    float* out = (float*)d_out;

    char* ws = (char*)d_ws;
    size_t o = 0;
    auto alloc = [&](size_t bytes) {
        char* p = ws + o;
        o += (bytes + 255) & ~(size_t)255;
        return p;
    };
    f16*   hbuf0  = (f16*) alloc((size_t)2 * PLANE * 2);       // 6.4 MB
    f16*   hbuf1  = (f16*) alloc((size_t)2 * PLANE * 2);       // 6.4 MB
    f16*   z1     = (f16*) alloc((size_t)2 * PLANE * 2);       // 6.4 MB
    int*   csr    = (int*) alloc((size_t)N_EDGES * 4);         // 12.8 MB
    unsigned int* ebuf = (unsigned int*)alloc((size_t)N_EDGES * 4);  // 12.8 MB
    int*   offA   = (int*) alloc((size_t)(N_NODES + 1) * 4);
    int*   pcnt   = (int*) alloc((size_t)256 * NPB * 4);       // 0.4 MB
    int*   btot   = (int*) alloc(1024);
    int*   boff   = (int*) alloc(1024);
    float* stats  = (float*)alloc(NLAYERS * 64 * 4);
    float* pooled = (float*)alloc((size_t)NGRAPHS * HD * 4);

    k_encoder<<<(N_NODES * 8 + 255) / 256, 256, 0, stream>>>(x, W_enc, b_enc,
                                                             hbuf0, stats, pooled);
    k_phist   <<<NPB, 256, 0, stream>>>(ei, pcnt);
    k_pscanA  <<<NBUCK, 512, 0, stream>>>(pcnt, btot);
    k_pscanB  <<<1, 256, 0, stream>>>(btot, boff, offA);
    k_pscatter<<<NPB, 256, 0, stream>>>(ei, pcnt, boff, ebuf);
    k_bfinal  <<<NBUCK, 512, 0, stream>>>(ebuf, boff, offA, csr);

    const int AGG_GRID = (N_NODES + 63) / 64;        // 1563
    f16* hcur = hbuf0;
    f16* hnext = hbuf1;
    for (int l = 0; l < NLAYERS; ++l) {
        k_agg<<<AGG_GRID, 256, 0, stream>>>(hcur, offA, csr, epsArr, stats,
                                            gamma, beta, z1, l, 0);
        k_agg<<<AGG_GRID, 256, 0, stream>>>(hcur, offA, csr, epsArr, stats,
                                            gamma, beta, z1, l, 1);
        k_mlp<<<1563, 256, 0, stream>>>(z1, W1, b1, W2, b2, hnext, stats, l);
        f16* tmp = hcur; hcur = hnext; hnext = tmp;
    }
    k_pool<<<(N_NODES + 255) / 256, 256, 0, stream>>>(hcur, batch, stats,
                                                      gamma, beta, pooled);
    k_cls <<<8, 256, 0, stream>>>(pooled, Wc, bc, out);
}

// Round 8
// 536.686 us; speedup vs baseline: 2.3523x; 1.2394x over previous
//
#include <hip/hip_runtime.h>

#define N_NODES 100000
#define N_EDGES 3200000
#define HD      32
#define NLAYERS 4
#define NGRAPHS 1000
#define BN_EPS  1e-5f
#define BSHIFT  9                         // 512-node buckets
#define NBUCK   ((N_NODES + 511) >> 9)    // 196
#define PCHUNK  8192                      // edges per partition block
#define NPB     ((N_EDGES + PCHUNK - 1) / PCHUNK)   // 391
#define PLANE   (N_NODES * 16)            // f16 elems per 16-channel plane
#define AGG_GRID ((N_NODES + 63) / 64)    // 1563 blocks per plane

typedef _Float16 f16;
typedef _Float16 f16x2 __attribute__((ext_vector_type(2)));
typedef _Float16 f16x4 __attribute__((ext_vector_type(4)));
typedef _Float16 f16x8 __attribute__((ext_vector_type(8)));
typedef float    f32x2 __attribute__((ext_vector_type(2)));
typedef float    f32x4 __attribute__((ext_vector_type(4)));
typedef int      i32x4 __attribute__((ext_vector_type(4)));

__device__ __forceinline__ f32x4 ld4cv(const f16* p) {
    return __builtin_convertvector(*(const f16x4*)p, f32x4);
}
__device__ __forceinline__ f32x4 cv4(f16x4 v) {
    return __builtin_convertvector(v, f32x4);
}
__device__ __forceinline__ void st4nt(f16* p, f32x4 v) {
    f16x4 r = __builtin_convertvector(v, f16x4);
    __builtin_nontemporal_store(r, (f16x4*)p);
}

// ---------------- encoder: hh(planes) = f16(x*W_enc + b_enc) (+ zero-init) ----
__global__ __launch_bounds__(256) void k_encoder(
    const float* __restrict__ x, const float* __restrict__ W_enc,
    const float* __restrict__ b_enc, f16* __restrict__ hh,
    float* __restrict__ stats, float* __restrict__ pooled)
{
    int gid = blockIdx.x * 256 + threadIdx.x;        // over N*8 (4 ch each)
    if (gid < NLAYERS * 64)   stats[gid]  = 0.f;
    if (gid < NGRAPHS * HD)   pooled[gid] = 0.f;
    if (gid < N_NODES * 8) {
        int i = gid >> 3, c0 = (gid & 7) * 4;
        float xv = x[i];
        f16x4 r;
        #pragma unroll
        for (int k = 0; k < 4; ++k)
            r[k] = (f16)(xv * W_enc[c0 + k] + b_enc[c0 + k]);
        int p = c0 >> 4, lc = c0 & 15;
        *(f16x4*)(hh + p * PLANE + i * 16 + lc) = r;
    }
}

// ---------------- deterministic radix partition (no global atomics) -----------
__global__ __launch_bounds__(256) void k_phist(const int* __restrict__ ei,
                                               int* __restrict__ pcnt)
{
    __shared__ int hist[256];
    int t = threadIdx.x, blk = blockIdx.x;
    hist[t] = 0;
    __syncthreads();
    int base4 = blk * (PCHUNK / 4);
    int n4 = min(PCHUNK / 4, N_EDGES / 4 - base4);
    const i32x4* d4 = (const i32x4*)(ei + N_EDGES);
    for (int k = t; k < n4; k += 256) {
        i32x4 d = __builtin_nontemporal_load(d4 + base4 + k);
        atomicAdd(&hist[d.x >> BSHIFT], 1);
        atomicAdd(&hist[d.y >> BSHIFT], 1);
        atomicAdd(&hist[d.z >> BSHIFT], 1);
        atomicAdd(&hist[d.w >> BSHIFT], 1);
    }
    __syncthreads();
    pcnt[t * NPB + blk] = hist[t];
}

__global__ __launch_bounds__(512) void k_pscanA(int* __restrict__ pcnt,
                                                int* __restrict__ btot)
{
    __shared__ int sc[2][512];
    int t = threadIdx.x, b = blockIdx.x;
    int base = b * NPB;
    int v = (t < NPB) ? pcnt[base + t] : 0;
    int pp = 0;
    sc[0][t] = v;
    __syncthreads();
    for (int st = 1; st < 512; st <<= 1) {
        int x = sc[pp][t];
        if (t >= st) x += sc[pp][t - st];
        sc[pp ^ 1][t] = x;
        pp ^= 1;
        __syncthreads();
    }
    int incl = sc[pp][t];
    if (t < NPB) pcnt[base + t] = incl - v;
    if (t == NPB - 1) btot[b] = incl;
}

__global__ __launch_bounds__(256) void k_pscanB(const int* __restrict__ btot,
                                                int* __restrict__ boff,
                                                int* __restrict__ off)
{
    __shared__ int sc[2][256];
    int t = threadIdx.x;
    int v = (t < NBUCK) ? btot[t] : 0;
    int pp = 0;
    sc[0][t] = v;
    __syncthreads();
    for (int st = 1; st < 256; st <<= 1) {
        int x = sc[pp][t];
        if (t >= st) x += sc[pp][t - st];
        sc[pp ^ 1][t] = x;
        pp ^= 1;
        __syncthreads();
    }
    int incl = sc[pp][t];
    if (t < NBUCK) boff[t] = incl - v;
    if (t == NBUCK - 1) { boff[NBUCK] = incl; off[N_NODES] = incl; }
}

__global__ __launch_bounds__(256) void k_pscatter(const int* __restrict__ ei,
                                                  const int* __restrict__ pcnt,
                                                  const int* __restrict__ boff,
                                                  unsigned int* __restrict__ ebuf)
{
    __shared__ int lcur[256];
    int t = threadIdx.x, blk = blockIdx.x;
    lcur[t] = pcnt[t * NPB + blk] + ((t < NBUCK) ? boff[t] : 0);
    __syncthreads();
    int base4 = blk * (PCHUNK / 4);
    int n4 = min(PCHUNK / 4, N_EDGES / 4 - base4);
    const i32x4* s4 = (const i32x4*)ei;
    const i32x4* d4 = (const i32x4*)(ei + N_EDGES);
    for (int k = t; k < n4; k += 256) {
        i32x4 s = __builtin_nontemporal_load(s4 + base4 + k);
        i32x4 d = __builtin_nontemporal_load(d4 + base4 + k);
        int pos;
        pos = atomicAdd(&lcur[d.x >> BSHIFT], 1);
        ebuf[pos] = ((unsigned)s.x << BSHIFT) | (unsigned)(d.x & 511);
        pos = atomicAdd(&lcur[d.y >> BSHIFT], 1);
        ebuf[pos] = ((unsigned)s.y << BSHIFT) | (unsigned)(d.y & 511);
        pos = atomicAdd(&lcur[d.z >> BSHIFT], 1);
        ebuf[pos] = ((unsigned)s.z << BSHIFT) | (unsigned)(d.z & 511);
        pos = atomicAdd(&lcur[d.w >> BSHIFT], 1);
        ebuf[pos] = ((unsigned)s.w << BSHIFT) | (unsigned)(d.w & 511);
    }
}

__global__ __launch_bounds__(512) void k_bfinal(const unsigned int* __restrict__ ebuf,
                                                const int* __restrict__ boff,
                                                int* __restrict__ off,
                                                int* __restrict__ csr)
{
    __shared__ int cnt[512], scanbuf[2][512], cur[512];
    int tid = threadIdx.x, b = blockIdx.x;
    int base = boff[b], nE = boff[b + 1] - base;
    cnt[tid] = 0;
    __syncthreads();
    for (int e = tid; e < nE; e += 512)
        atomicAdd(&cnt[ebuf[base + e] & 511], 1);
    __syncthreads();
    int pp = 0;
    scanbuf[0][tid] = cnt[tid];
    __syncthreads();
    for (int st = 1; st < 512; st <<= 1) {
        int v = scanbuf[pp][tid];
        if (tid >= st) v += scanbuf[pp][tid - st];
        scanbuf[pp ^ 1][tid] = v;
        pp ^= 1;
        __syncthreads();
    }
    int excl = scanbuf[pp][tid] - cnt[tid];
    cur[tid] = excl;
    int gnode = (b << BSHIFT) + tid;
    if (gnode < N_NODES) off[gnode] = base + excl;
    __syncthreads();
    for (int e = tid; e < nE; e += 512) {
        unsigned int p = ebuf[base + e];
        int pos = atomicAdd(&cur[p & 511], 1);
        csr[base + pos] = (int)(p >> BSHIFT);
    }
}

// ---------------- plane aggregation with inline BN(prev)+ReLU ------------------
// Both planes in one dispatch: plane = blockIdx >= AGG_GRID.
// 4 lanes/node (4 ch each, f16x4 loads). No LDS, no barriers.
// z1 written node-major [node][32] for the MFMA MLP.
__global__ __launch_bounds__(256) void k_agg(
    const f16* __restrict__ hraw, const int* __restrict__ off,
    const int* __restrict__ csr, const float* __restrict__ epsArr,
    const float* __restrict__ stats, const float* __restrict__ gamma,
    const float* __restrict__ beta, f16* __restrict__ z1out, int layer)
{
    int tid = threadIdx.x;
    int bb = blockIdx.x;
    int plane = (bb >= AGG_GRID);
    int nblk = bb - plane * AGG_GRID;
    int unit = tid >> 2, li = tid & 3;
    int node = nblk * 64 + unit;
    if (node >= N_NODES) return;
    int cb = plane * 16 + li * 4;                    // first of 4 channels
    f32x4 sc, sh;
    bool relu = (layer > 0);
    if (relu) {
        const float invN = 1.0f / (float)N_NODES;
        #pragma unroll
        for (int k = 0; k < 4; ++k) {
            int ch = cb + k;
            float mu  = stats[(layer - 1) * 64 + ch] * invN;
            float var = stats[(layer - 1) * 64 + 32 + ch] * invN - mu * mu;
            float s = gamma[(layer - 1) * 32 + ch] * rsqrtf(var + BN_EPS);
            sc[k] = s;
            sh[k] = beta[(layer - 1) * 32 + ch] - mu * s;
        }
    } else {
        #pragma unroll
        for (int k = 0; k < 4; ++k) { sc[k] = 1.f; sh[k] = 0.f; }
    }
    float oneEps = 1.f + epsArr[layer];
    const f16* hp = hraw + plane * PLANE;
    int co = li * 4;

    auto bnf = [&](f32x4 v) -> f32x4 {
        f32x4 r;
        #pragma unroll
        for (int k = 0; k < 4; ++k) {
            r[k] = fmaf(v[k], sc[k], sh[k]);
            if (relu) r[k] = fmaxf(r[k], 0.f);
        }
        return r;
    };

    int j = off[node], jend = off[node + 1];
    f32x4 A = {0,0,0,0}, B = {0,0,0,0}, C = {0,0,0,0}, D = {0,0,0,0};
    while (j < jend && (j & 3)) A += bnf(ld4cv(hp + csr[j++] * 16 + co));
    int n8 = (jend - j) >> 3;
    for (int it = 0; it < n8; ++it) {
        i32x4 q0 = __builtin_nontemporal_load((const i32x4*)(csr + j));
        i32x4 q1 = __builtin_nontemporal_load((const i32x4*)(csr + j + 4));
        f16x4 g0 = *(const f16x4*)(hp + q0.x * 16 + co);
        f16x4 g1 = *(const f16x4*)(hp + q0.y * 16 + co);
        f16x4 g2 = *(const f16x4*)(hp + q0.z * 16 + co);
        f16x4 g3 = *(const f16x4*)(hp + q0.w * 16 + co);
        f16x4 g4 = *(const f16x4*)(hp + q1.x * 16 + co);
        f16x4 g5 = *(const f16x4*)(hp + q1.y * 16 + co);
        f16x4 g6 = *(const f16x4*)(hp + q1.z * 16 + co);
        f16x4 g7 = *(const f16x4*)(hp + q1.w * 16 + co);
        A += bnf(cv4(g0)); B += bnf(cv4(g1)); C += bnf(cv4(g2)); D += bnf(cv4(g3));
        A += bnf(cv4(g4)); B += bnf(cv4(g5)); C += bnf(cv4(g6)); D += bnf(cv4(g7));
        j += 8;
    }
    if (jend - j >= 4) {
        i32x4 q0 = *(const i32x4*)(csr + j);
        A += bnf(ld4cv(hp + q0.x * 16 + co));
        B += bnf(ld4cv(hp + q0.y * 16 + co));
        C += bnf(ld4cv(hp + q0.z * 16 + co));
        D += bnf(ld4cv(hp + q0.w * 16 + co));
        j += 4;
    }
    while (j < jend) A += bnf(ld4cv(hp + csr[j++] * 16 + co));

    f32x4 z1 = (A + B) + (C + D);
    z1 += oneEps * bnf(ld4cv(hp + node * 16 + co));
    st4nt(z1out + node * 32 + cb, z1);               // node-major [node][32]
}

// ---------------- MFMA MLP: z1[node][32] -> hnext(planes), + stats -------------
// One wave per 16-node tile: 2 MFMA (W1) -> relu -> LDS transpose -> 2 MFMA (W2).
__global__ __launch_bounds__(256) void k_mlp(
    const f16* __restrict__ z1, const float* __restrict__ W1,
    const float* __restrict__ b1, const float* __restrict__ W2,
    const float* __restrict__ b2, f16* __restrict__ hnext,
    float* __restrict__ stats, int layer)
{
    __shared__ float T[4][16 * 36];                  // per-wave transpose tile
    __shared__ float redS[4][32], redQ[4][32];
    int tid = threadIdx.x, wave = tid >> 6, lane = tid & 63;
    int col = lane & 15, quad = lane >> 4;
    const float* W1l = W1 + layer * 1024;
    const float* W2l = W2 + layer * 1024;
    // B-fragments: lane holds B[k=quad*8+j][n=col(+16)]
    f16x8 w1a, w1b, w2a, w2b;
    #pragma unroll
    for (int j = 0; j < 8; ++j) {
        int k = quad * 8 + j;
        w1a[j] = (f16)W1l[k * 32 + col];
        w1b[j] = (f16)W1l[k * 32 + col + 16];
        w2a[j] = (f16)W2l[k * 32 + col];
        w2b[j] = (f16)W2l[k * 32 + col + 16];
    }
    float b1a = b1[layer * 32 + col], b1b = b1[layer * 32 + col + 16];
    float b2a = b2[layer * 32 + col], b2b = b2[layer * 32 + col + 16];
    f32x4 bias1a = {b1a, b1a, b1a, b1a}, bias1b = {b1b, b1b, b1b, b1b};
    f32x4 bias2a = {b2a, b2a, b2a, b2a}, bias2b = {b2b, b2b, b2b, b2b};
    float* Tw = T[wave];

    const int NT = N_NODES / 16;                     // 6250 exact
    int gw = blockIdx.x * 4 + wave, nw = gridDim.x * 4;
    float sA = 0.f, qA = 0.f, sB = 0.f, qB = 0.f;

    for (int tile = gw; tile < NT; tile += nw) {
        int nb = tile * 16;
        f16x8 a = *(const f16x8*)(z1 + (size_t)(nb + col) * 32 + quad * 8);
        f32x4 m0 = __builtin_amdgcn_mfma_f32_16x16x32_f16(a, w1a, bias1a, 0, 0, 0);
        f32x4 m1 = __builtin_amdgcn_mfma_f32_16x16x32_f16(a, w1b, bias1b, 0, 0, 0);
        #pragma unroll
        for (int r = 0; r < 4; ++r) {                // relu + write D-layout
            int row = quad * 4 + r;
            Tw[row * 36 + col]      = fmaxf(m0[r], 0.f);
            Tw[row * 36 + col + 16] = fmaxf(m1[r], 0.f);
        }
        // wave-sync read back in A-layout (2-way bank aliasing: free)
        f32x4 t0 = *(const f32x4*)(Tw + col * 36 + quad * 8);
        f32x4 t1 = *(const f32x4*)(Tw + col * 36 + quad * 8 + 4);
        f16x8 a2;
        #pragma unroll
        for (int jj = 0; jj < 4; ++jj) { a2[jj] = (f16)t0[jj]; a2[4 + jj] = (f16)t1[jj]; }
        f32x4 z0 = __builtin_amdgcn_mfma_f32_16x16x32_f16(a2, w2a, bias2a, 0, 0, 0);
        f32x4 zb = __builtin_amdgcn_mfma_f32_16x16x32_f16(a2, w2b, bias2b, 0, 0, 0);
        #pragma unroll
        for (int r = 0; r < 4; ++r) {
            int node = nb + quad * 4 + r;
            hnext[node * 16 + col]         = (f16)z0[r];   // plane 0
            hnext[PLANE + node * 16 + col] = (f16)zb[r];   // plane 1
            sA += z0[r]; qA += z0[r] * z0[r];
            sB += zb[r]; qB += zb[r] * zb[r];
        }
    }

    sA += __shfl_xor(sA, 16); sA += __shfl_xor(sA, 32);
    qA += __shfl_xor(qA, 16); qA += __shfl_xor(qA, 32);
    sB += __shfl_xor(sB, 16); sB += __shfl_xor(sB, 32);
    qB += __shfl_xor(qB, 16); qB += __shfl_xor(qB, 32);
    if (lane < 16) {
        redS[wave][col] = sA; redS[wave][col + 16] = sB;
        redQ[wave][col] = qA; redQ[wave][col + 16] = qB;
    }
    __syncthreads();
    if (tid < 64) {
        int sel = tid >> 5, cc = tid & 31;
        float s = 0.f;
        #pragma unroll
        for (int w = 0; w < 4; ++w) s += sel ? redQ[w][cc] : redS[w][cc];
        atomicAdd(&stats[layer * 64 + sel * 32 + cc], s);
    }
}

// ---------------- global_add_pool with inline BN(3)+ReLU -----------------------
__global__ __launch_bounds__(256) void k_pool(const f16* __restrict__ hraw,
                                              const int* __restrict__ batch,
                                              const float* __restrict__ stats,
                                              const float* __restrict__ gamma,
                                              const float* __restrict__ beta,
                                              float* __restrict__ pooled)
{
    int c = threadIdx.x & 31, slot = threadIdx.x >> 5;
    const float invN = 1.0f / (float)N_NODES;
    float mu  = stats[3 * 64 + c] * invN;
    float var = stats[3 * 64 + 32 + c] * invN - mu * mu;
    float sc = gamma[3 * 32 + c] * rsqrtf(var + BN_EPS);
    float sh = beta[3 * 32 + c] - mu * sc;
    const f16* hp = hraw + (c >> 4) * PLANE;
    int lc = c & 15;
    int start = blockIdx.x * 256 + slot * 32;
    if (start >= N_NODES) return;
    int end = min(start + 32, N_NODES);
    int cur = batch[start]; float acc = 0.f;
    for (int i = start; i < end; ++i) {
        int g = batch[i];
        if (g != cur) { atomicAdd(&pooled[cur * HD + c], acc); acc = 0.f; cur = g; }
        acc += fmaxf(fmaf((float)hp[i * 16 + lc], sc, sh), 0.f);
    }
    atomicAdd(&pooled[cur * HD + c], acc);
}

// ---------------- classifier ---------------------------------------------------
__global__ __launch_bounds__(256) void k_cls(const float* __restrict__ pooled,
                                             const float* __restrict__ Wc,
                                             const float* __restrict__ bc,
                                             float* __restrict__ out)
{
    int gid = blockIdx.x * 256 + threadIdx.x;
    if (gid >= NGRAPHS * 2) return;
    int g = gid >> 1, c = gid & 1;
    float s = bc[c];
    #pragma unroll
    for (int k = 0; k < 32; ++k) s = fmaf(pooled[g * 32 + k], Wc[k * 2 + c], s);
    out[gid] = s;
}

extern "C" void kernel_launch(void* const* d_in, const int* in_sizes, int n_in,
                              void* d_out, int out_size, void* d_ws, size_t ws_size,
                              hipStream_t stream)
{
    const float* x      = (const float*)d_in[0];
    const int*   ei     = (const int*)d_in[1];
    const int*   batch  = (const int*)d_in[2];
    const float* W_enc  = (const float*)d_in[3];
    const float* b_enc  = (const float*)d_in[4];
    const float* epsArr = (const float*)d_in[5];
    const float* W1     = (const float*)d_in[6];
    const float* b1     = (const float*)d_in[7];
    const float* W2     = (const float*)d_in[8];
    const float* b2     = (const float*)d_in[9];
    const float* gamma  = (const float*)d_in[10];
    const float* beta   = (const float*)d_in[11];
    const float* Wc     = (const float*)d_in[12];
    const float* bc     = (const float*)d_in[13];
    float* out = (float*)d_out;

    char* ws = (char*)d_ws;
    size_t o = 0;
    auto alloc = [&](size_t bytes) {
        char* p = ws + o;
        o += (bytes + 255) & ~(size_t)255;
        return p;
    };
    f16*   hbuf0  = (f16*) alloc((size_t)2 * PLANE * 2);       // 6.4 MB
    f16*   hbuf1  = (f16*) alloc((size_t)2 * PLANE * 2);       // 6.4 MB
    f16*   z1     = (f16*) alloc((size_t)2 * PLANE * 2);       // 6.4 MB [node][32]
    int*   csr    = (int*) alloc((size_t)N_EDGES * 4);         // 12.8 MB
    unsigned int* ebuf = (unsigned int*)alloc((size_t)N_EDGES * 4);  // 12.8 MB
    int*   offA   = (int*) alloc((size_t)(N_NODES + 1) * 4);
    int*   pcnt   = (int*) alloc((size_t)256 * NPB * 4);       // 0.4 MB
    int*   btot   = (int*) alloc(1024);
    int*   boff   = (int*) alloc(1024);
    float* stats  = (float*)alloc(NLAYERS * 64 * 4);
    float* pooled = (float*)alloc((size_t)NGRAPHS * HD * 4);

    k_encoder<<<(N_NODES * 8 + 255) / 256, 256, 0, stream>>>(x, W_enc, b_enc,
                                                             hbuf0, stats, pooled);
    k_phist   <<<NPB, 256, 0, stream>>>(ei, pcnt);
    k_pscanA  <<<NBUCK, 512, 0, stream>>>(pcnt, btot);
    k_pscanB  <<<1, 256, 0, stream>>>(btot, boff, offA);
    k_pscatter<<<NPB, 256, 0, stream>>>(ei, pcnt, boff, ebuf);
    k_bfinal  <<<NBUCK, 512, 0, stream>>>(ebuf, boff, offA, csr);

    f16* hcur = hbuf0;
    f16* hnext = hbuf1;
    for (int l = 0; l < NLAYERS; ++l) {
        k_agg<<<2 * AGG_GRID, 256, 0, stream>>>(hcur, offA, csr, epsArr, stats,
                                                gamma, beta, z1, l);
        k_mlp<<<782, 256, 0, stream>>>(z1, W1, b1, W2, b2, hnext, stats, l);
        f16* tmp = hcur; hcur = hnext; hnext = tmp;
    }
    k_pool<<<(N_NODES + 255) / 256, 256, 0, stream>>>(hcur, batch, stats,
                                                      gamma, beta, pooled);
    k_cls <<<8, 256, 0, stream>>>(pooled, Wc, bc, out);
}

// Round 9
// 490.219 us; speedup vs baseline: 2.5752x; 1.0948x over previous
//
#include <hip/hip_runtime.h>

#define N_NODES 100000
#define N_EDGES 3200000
#define HD      32
#define NLAYERS 4
#define NGRAPHS 1000
#define BN_EPS  1e-5f
#define BSHIFT  9                         // 512-node buckets
#define NBUCK   ((N_NODES + 511) >> 9)    // 196
#define PCHUNK  8192                      // edges per partition block
#define NPB     ((N_EDGES + PCHUNK - 1) / PCHUNK)   // 391
#define ENC_BLOCKS ((N_NODES * 8 + 255) / 256)      // 3125

typedef _Float16 f16;
typedef _Float16 f16x4 __attribute__((ext_vector_type(4)));
typedef _Float16 f16x8 __attribute__((ext_vector_type(8)));
typedef float    f32x4 __attribute__((ext_vector_type(4)));
typedef int      i32x4 __attribute__((ext_vector_type(4)));

// ---------------- fused encoder (h[node][32]) + phist --------------------------
__global__ __launch_bounds__(256) void k_encphist(
    const float* __restrict__ x, const float* __restrict__ W_enc,
    const float* __restrict__ b_enc, const int* __restrict__ ei,
    f16* __restrict__ hh, float* __restrict__ stats,
    float* __restrict__ pooled, int* __restrict__ pcnt)
{
    __shared__ int hist[256];
    int bb = blockIdx.x, t = threadIdx.x;
    if (bb < NPB) {                                  // ---- phist part
        hist[t] = 0;
        __syncthreads();
        int base4 = bb * (PCHUNK / 4);
        int n4 = min(PCHUNK / 4, N_EDGES / 4 - base4);
        const i32x4* d4 = (const i32x4*)(ei + N_EDGES);
        for (int k = t; k < n4; k += 256) {
            i32x4 d = __builtin_nontemporal_load(d4 + base4 + k);
            atomicAdd(&hist[d.x >> BSHIFT], 1);
            atomicAdd(&hist[d.y >> BSHIFT], 1);
            atomicAdd(&hist[d.z >> BSHIFT], 1);
            atomicAdd(&hist[d.w >> BSHIFT], 1);
        }
        __syncthreads();
        pcnt[t * NPB + bb] = hist[t];
    } else {                                         // ---- encoder part
        int gid = (bb - NPB) * 256 + t;
        if (gid < NLAYERS * 64)   stats[gid]  = 0.f;
        if (gid < NGRAPHS * HD)   pooled[gid] = 0.f;
        if (gid < N_NODES * 8) {
            int i = gid >> 3, c0 = (gid & 7) * 4;
            float xv = x[i];
            f16x4 r;
            #pragma unroll
            for (int k = 0; k < 4; ++k)
                r[k] = (f16)(xv * W_enc[c0 + k] + b_enc[c0 + k]);
            *(f16x4*)(hh + i * 32 + c0) = r;
        }
    }
}

// per-bucket scan of per-block counts (in place) + bucket totals
__global__ __launch_bounds__(512) void k_pscanA(int* __restrict__ pcnt,
                                                int* __restrict__ btot)
{
    __shared__ int sc[2][512];
    int t = threadIdx.x, b = blockIdx.x;
    int base = b * NPB;
    int v = (t < NPB) ? pcnt[base + t] : 0;
    int pp = 0;
    sc[0][t] = v;
    __syncthreads();
    for (int st = 1; st < 512; st <<= 1) {
        int x = sc[pp][t];
        if (t >= st) x += sc[pp][t - st];
        sc[pp ^ 1][t] = x;
        pp ^= 1;
        __syncthreads();
    }
    int incl = sc[pp][t];
    if (t < NPB) pcnt[base + t] = incl - v;
    if (t == NPB - 1) btot[b] = incl;
}

// scatter packed edges to exact positions (LDS cursors; bucket scan inline)
__global__ __launch_bounds__(256) void k_pscatter(const int* __restrict__ ei,
                                                  const int* __restrict__ pcnt,
                                                  const int* __restrict__ btot,
                                                  unsigned int* __restrict__ ebuf)
{
    __shared__ int sb[2][256];
    __shared__ int lcur[256];
    int t = threadIdx.x, blk = blockIdx.x;
    sb[0][t] = (t < NBUCK) ? btot[t] : 0;
    __syncthreads();
    int pp = 0;
    for (int st = 1; st < 256; st <<= 1) {
        int v = sb[pp][t];
        if (t >= st) v += sb[pp][t - st];
        sb[pp ^ 1][t] = v;
        pp ^= 1;
        __syncthreads();
    }
    int bexcl = (t == 0) ? 0 : sb[pp][t - 1];
    lcur[t] = pcnt[t * NPB + blk] + bexcl;
    __syncthreads();
    int base4 = blk * (PCHUNK / 4);
    int n4 = min(PCHUNK / 4, N_EDGES / 4 - base4);
    const i32x4* s4 = (const i32x4*)ei;
    const i32x4* d4 = (const i32x4*)(ei + N_EDGES);
    for (int k = t; k < n4; k += 256) {
        i32x4 s = __builtin_nontemporal_load(s4 + base4 + k);
        i32x4 d = __builtin_nontemporal_load(d4 + base4 + k);
        int pos;
        pos = atomicAdd(&lcur[d.x >> BSHIFT], 1);
        ebuf[pos] = ((unsigned)s.x << BSHIFT) | (unsigned)(d.x & 511);
        pos = atomicAdd(&lcur[d.y >> BSHIFT], 1);
        ebuf[pos] = ((unsigned)s.y << BSHIFT) | (unsigned)(d.y & 511);
        pos = atomicAdd(&lcur[d.z >> BSHIFT], 1);
        ebuf[pos] = ((unsigned)s.z << BSHIFT) | (unsigned)(d.z & 511);
        pos = atomicAdd(&lcur[d.w >> BSHIFT], 1);
        ebuf[pos] = ((unsigned)s.w << BSHIFT) | (unsigned)(d.w & 511);
    }
}

// per-bucket local sort -> final CSR + off[] (bucket scan inline)
__global__ __launch_bounds__(512) void k_bfinal(const unsigned int* __restrict__ ebuf,
                                                const int* __restrict__ btot,
                                                int* __restrict__ off,
                                                int* __restrict__ csr)
{
    __shared__ int sb[2][256];
    __shared__ int cnt[512], scanbuf[2][512], cur[512];
    int tid = threadIdx.x, b = blockIdx.x;
    if (tid < 256) sb[0][tid] = (tid < NBUCK) ? btot[tid] : 0;
    __syncthreads();
    int pp = 0;
    for (int st = 1; st < 256; st <<= 1) {
        if (tid < 256) {
            int v = sb[pp][tid];
            if (tid >= st) v += sb[pp][tid - st];
            sb[pp ^ 1][tid] = v;
        }
        pp ^= 1;
        __syncthreads();
    }
    int base = (b == 0) ? 0 : sb[pp][b - 1];
    int nE = sb[pp][b] - base;
    if (b == NBUCK - 1 && tid == 0) off[N_NODES] = sb[pp][NBUCK - 1];
    cnt[tid] = 0;
    __syncthreads();
    for (int e = tid; e < nE; e += 512)
        atomicAdd(&cnt[ebuf[base + e] & 511], 1);
    __syncthreads();
    int p2 = 0;
    scanbuf[0][tid] = cnt[tid];
    __syncthreads();
    for (int st = 1; st < 512; st <<= 1) {
        int v = scanbuf[p2][tid];
        if (tid >= st) v += scanbuf[p2][tid - st];
        scanbuf[p2 ^ 1][tid] = v;
        p2 ^= 1;
        __syncthreads();
    }
    int excl = scanbuf[p2][tid] - cnt[tid];
    cur[tid] = excl;
    int gnode = (b << BSHIFT) + tid;
    if (gnode < N_NODES) off[gnode] = base + excl;
    __syncthreads();
    for (int e = tid; e < nE; e += 512) {
        unsigned int p = ebuf[base + e];
        int pos = atomicAdd(&cur[p & 511], 1);
        csr[base + pos] = (int)(p >> BSHIFT);
    }
}

// ---------------- fused layer: gather (A-frag direct) + MFMA MLP + stats -------
// h layout [node][32] f16 (64-B rows). Lane: node = lane&15, quad = lane>>4.
// Gathered f16x8 at h[src*32+quad*8] IS the MFMA A-fragment element set.
__global__ __launch_bounds__(256) void k_layer(
    const f16* __restrict__ hcur, const int* __restrict__ off,
    const int* __restrict__ csr, const float* __restrict__ epsArr,
    const float* __restrict__ gamma, const float* __restrict__ beta,
    const float* __restrict__ W1, const float* __restrict__ b1,
    const float* __restrict__ W2, const float* __restrict__ b2,
    f16* __restrict__ hnext, float* __restrict__ stats, int layer)
{
    __shared__ float T[4][16 * 36];
    __shared__ float redS[4][32], redQ[4][32];
    int tid = threadIdx.x, wave = tid >> 6, lane = tid & 63;
    int col = lane & 15, quad = lane >> 4;
    // BN(prev)+ReLU constants for input channels quad*8 .. +7
    float sc[8], sh[8];
    bool relu = (layer > 0);
    if (relu) {
        const float invN = 1.0f / (float)N_NODES;
        #pragma unroll
        for (int k = 0; k < 8; ++k) {
            int ch = quad * 8 + k;
            float mu  = stats[(layer - 1) * 64 + ch] * invN;
            float var = stats[(layer - 1) * 64 + 32 + ch] * invN - mu * mu;
            float s = gamma[(layer - 1) * 32 + ch] * rsqrtf(var + BN_EPS);
            sc[k] = s;
            sh[k] = beta[(layer - 1) * 32 + ch] - mu * s;
        }
    } else {
        #pragma unroll
        for (int k = 0; k < 8; ++k) { sc[k] = 1.f; sh[k] = 0.f; }
    }
    float oneEps = 1.f + epsArr[layer];
    const float* W1l = W1 + layer * 1024;
    const float* W2l = W2 + layer * 1024;
    f16x8 w1a, w1b, w2a, w2b;                        // B[k=quad*8+j][n=col(+16)]
    #pragma unroll
    for (int j = 0; j < 8; ++j) {
        int k = quad * 8 + j;
        w1a[j] = (f16)W1l[k * 32 + col];
        w1b[j] = (f16)W1l[k * 32 + col + 16];
        w2a[j] = (f16)W2l[k * 32 + col];
        w2b[j] = (f16)W2l[k * 32 + col + 16];
    }
    float b1a = b1[layer * 32 + col], b1b = b1[layer * 32 + col + 16];
    float b2a = b2[layer * 32 + col], b2b = b2[layer * 32 + col + 16];
    f32x4 bias1a = {b1a, b1a, b1a, b1a}, bias1b = {b1b, b1b, b1b, b1b};
    f32x4 bias2a = {b2a, b2a, b2a, b2a}, bias2b = {b2b, b2b, b2b, b2b};
    float* Tw = T[wave];

    float sA = 0.f, qA = 0.f, sB = 0.f, qB = 0.f;
    const int NT = N_NODES / 16;                     // 6250 exact

    for (int tile = blockIdx.x * 4 + wave; tile < NT; tile += gridDim.x * 4) {
        int nb = tile * 16;
        int node = nb + col;
        int j = off[node], jend = off[node + 1];
        f32x4 A0 = {0,0,0,0}, A1 = {0,0,0,0}, B0 = {0,0,0,0}, B1 = {0,0,0,0};
        while (j + 4 <= jend) {                      // 4 rows in flight per lane
            int s0 = csr[j], s1 = csr[j+1], s2 = csr[j+2], s3 = csr[j+3];
            f16x8 g0 = *(const f16x8*)(hcur + s0 * 32 + quad * 8);
            f16x8 g1 = *(const f16x8*)(hcur + s1 * 32 + quad * 8);
            f16x8 g2 = *(const f16x8*)(hcur + s2 * 32 + quad * 8);
            f16x8 g3 = *(const f16x8*)(hcur + s3 * 32 + quad * 8);
            #pragma unroll
            for (int k = 0; k < 4; ++k) {
                float v0 = fmaf((float)g0[k],   sc[k],   sh[k]);
                float v1 = fmaf((float)g0[k+4], sc[k+4], sh[k+4]);
                float v2 = fmaf((float)g1[k],   sc[k],   sh[k]);
                float v3 = fmaf((float)g1[k+4], sc[k+4], sh[k+4]);
                float v4 = fmaf((float)g2[k],   sc[k],   sh[k]);
                float v5 = fmaf((float)g2[k+4], sc[k+4], sh[k+4]);
                float v6 = fmaf((float)g3[k],   sc[k],   sh[k]);
                float v7 = fmaf((float)g3[k+4], sc[k+4], sh[k+4]);
                if (relu) {
                    v0 = fmaxf(v0, 0.f); v1 = fmaxf(v1, 0.f);
                    v2 = fmaxf(v2, 0.f); v3 = fmaxf(v3, 0.f);
                    v4 = fmaxf(v4, 0.f); v5 = fmaxf(v5, 0.f);
                    v6 = fmaxf(v6, 0.f); v7 = fmaxf(v7, 0.f);
                }
                A0[k] += v0 + v4; A1[k] += v1 + v5;
                B0[k] += v2 + v6; B1[k] += v3 + v7;
            }
            j += 4;
        }
        while (j < jend) {                           // tail
            f16x8 g = *(const f16x8*)(hcur + csr[j] * 32 + quad * 8);
            #pragma unroll
            for (int k = 0; k < 4; ++k) {
                float v0 = fmaf((float)g[k],   sc[k],   sh[k]);
                float v1 = fmaf((float)g[k+4], sc[k+4], sh[k+4]);
                if (relu) { v0 = fmaxf(v0, 0.f); v1 = fmaxf(v1, 0.f); }
                A0[k] += v0; A1[k] += v1;
            }
            ++j;
        }
        {                                            // self term
            f16x8 g = *(const f16x8*)(hcur + node * 32 + quad * 8);
            #pragma unroll
            for (int k = 0; k < 4; ++k) {
                float v0 = fmaf((float)g[k],   sc[k],   sh[k]);
                float v1 = fmaf((float)g[k+4], sc[k+4], sh[k+4]);
                if (relu) { v0 = fmaxf(v0, 0.f); v1 = fmaxf(v1, 0.f); }
                A0[k] += oneEps * v0; A1[k] += oneEps * v1;
            }
        }
        f16x8 a;                                     // A-frag: z1[node][quad*8+j]
        #pragma unroll
        for (int k = 0; k < 4; ++k) {
            a[k]     = (f16)(A0[k] + B0[k]);
            a[k + 4] = (f16)(A1[k] + B1[k]);
        }
        f32x4 m0 = __builtin_amdgcn_mfma_f32_16x16x32_f16(a, w1a, bias1a, 0, 0, 0);
        f32x4 m1 = __builtin_amdgcn_mfma_f32_16x16x32_f16(a, w1b, bias1b, 0, 0, 0);
        #pragma unroll
        for (int r = 0; r < 4; ++r) {                // relu + D-layout -> LDS
            int row = quad * 4 + r;
            Tw[row * 36 + col]      = fmaxf(m0[r], 0.f);
            Tw[row * 36 + col + 16] = fmaxf(m1[r], 0.f);
        }
        f32x4 t0 = *(const f32x4*)(Tw + col * 36 + quad * 8);      // wave-sync
        f32x4 t1 = *(const f32x4*)(Tw + col * 36 + quad * 8 + 4);
        f16x8 a2;
        #pragma unroll
        for (int k = 0; k < 4; ++k) { a2[k] = (f16)t0[k]; a2[k + 4] = (f16)t1[k]; }
        f32x4 z0 = __builtin_amdgcn_mfma_f32_16x16x32_f16(a2, w2a, bias2a, 0, 0, 0);
        f32x4 zb = __builtin_amdgcn_mfma_f32_16x16x32_f16(a2, w2b, bias2b, 0, 0, 0);
        #pragma unroll
        for (int r = 0; r < 4; ++r) {
            int n2 = nb + quad * 4 + r;
            hnext[n2 * 32 + col]      = (f16)z0[r];
            hnext[n2 * 32 + col + 16] = (f16)zb[r];
            sA += z0[r]; qA += z0[r] * z0[r];
            sB += zb[r]; qB += zb[r] * zb[r];
        }
    }

    sA += __shfl_xor(sA, 16); sA += __shfl_xor(sA, 32);
    qA += __shfl_xor(qA, 16); qA += __shfl_xor(qA, 32);
    sB += __shfl_xor(sB, 16); sB += __shfl_xor(sB, 32);
    qB += __shfl_xor(qB, 16); qB += __shfl_xor(qB, 32);
    if (lane < 16) {
        redS[wave][col] = sA; redS[wave][col + 16] = sB;
        redQ[wave][col] = qA; redQ[wave][col + 16] = qB;
    }
    __syncthreads();
    if (tid < 64) {
        int sel = tid >> 5, cc = tid & 31;
        float s = 0.f;
        #pragma unroll
        for (int w = 0; w < 4; ++w) s += sel ? redQ[w][cc] : redS[w][cc];
        atomicAdd(&stats[layer * 64 + sel * 32 + cc], s);
    }
}

// ---------------- global_add_pool with inline BN(3)+ReLU -----------------------
__global__ __launch_bounds__(256) void k_pool(const f16* __restrict__ h,
                                              const int* __restrict__ batch,
                                              const float* __restrict__ stats,
                                              const float* __restrict__ gamma,
                                              const float* __restrict__ beta,
                                              float* __restrict__ pooled)
{
    int c = threadIdx.x & 31, slot = threadIdx.x >> 5;
    const float invN = 1.0f / (float)N_NODES;
    float mu  = stats[3 * 64 + c] * invN;
    float var = stats[3 * 64 + 32 + c] * invN - mu * mu;
    float sc = gamma[3 * 32 + c] * rsqrtf(var + BN_EPS);
    float sh = beta[3 * 32 + c] - mu * sc;
    int start = blockIdx.x * 256 + slot * 32;
    if (start >= N_NODES) return;
    int end = min(start + 32, N_NODES);
    int cur = batch[start]; float acc = 0.f;
    for (int i = start; i < end; ++i) {
        int g = batch[i];
        if (g != cur) { atomicAdd(&pooled[cur * HD + c], acc); acc = 0.f; cur = g; }
        acc += fmaxf(fmaf((float)h[i * 32 + c], sc, sh), 0.f);
    }
    atomicAdd(&pooled[cur * HD + c], acc);
}

// ---------------- classifier ---------------------------------------------------
__global__ __launch_bounds__(256) void k_cls(const float* __restrict__ pooled,
                                             const float* __restrict__ Wc,
                                             const float* __restrict__ bc,
                                             float* __restrict__ out)
{
    int gid = blockIdx.x * 256 + threadIdx.x;
    if (gid >= NGRAPHS * 2) return;
    int g = gid >> 1, c = gid & 1;
    float s = bc[c];
    #pragma unroll
    for (int k = 0; k < 32; ++k) s = fmaf(pooled[g * 32 + k], Wc[k * 2 + c], s);
    out[gid] = s;
}

extern "C" void kernel_launch(void* const* d_in, const int* in_sizes, int n_in,
                              void* d_out, int out_size, void* d_ws, size_t ws_size,
                              hipStream_t stream)
{
    const float* x      = (const float*)d_in[0];
    const int*   ei     = (const int*)d_in[1];
    const int*   batch  = (const int*)d_in[2];
    const float* W_enc  = (const float*)d_in[3];
    const float* b_enc  = (const float*)d_in[4];
    const float* epsArr = (const float*)d_in[5];
    const float* W1     = (const float*)d_in[6];
    const float* b1     = (const float*)d_in[7];
    const float* W2     = (const float*)d_in[8];
    const float* b2     = (const float*)d_in[9];
    const float* gamma  = (const float*)d_in[10];
    const float* beta   = (const float*)d_in[11];
    const float* Wc     = (const float*)d_in[12];
    const float* bc     = (const float*)d_in[13];
    float* out = (float*)d_out;

    char* ws = (char*)d_ws;
    size_t o = 0;
    auto alloc = [&](size_t bytes) {
        char* p = ws + o;
        o += (bytes + 255) & ~(size_t)255;
        return p;
    };
    f16*   hbuf0  = (f16*) alloc((size_t)N_NODES * 32 * 2);    // 6.4 MB [node][32]
    f16*   hbuf1  = (f16*) alloc((size_t)N_NODES * 32 * 2);    // 6.4 MB
    int*   csr    = (int*) alloc((size_t)N_EDGES * 4);         // 12.8 MB
    unsigned int* ebuf = (unsigned int*)alloc((size_t)N_EDGES * 4);  // 12.8 MB
    int*   offA   = (int*) alloc((size_t)(N_NODES + 1) * 4);
    int*   pcnt   = (int*) alloc((size_t)256 * NPB * 4);       // 0.4 MB
    int*   btot   = (int*) alloc(1024);
    float* stats  = (float*)alloc(NLAYERS * 64 * 4);
    float* pooled = (float*)alloc((size_t)NGRAPHS * HD * 4);

    k_encphist<<<NPB + ENC_BLOCKS, 256, 0, stream>>>(x, W_enc, b_enc, ei, hbuf0,
                                                     stats, pooled, pcnt);
    k_pscanA  <<<NBUCK, 512, 0, stream>>>(pcnt, btot);
    k_pscatter<<<NPB, 256, 0, stream>>>(ei, pcnt, btot, ebuf);
    k_bfinal  <<<NBUCK, 512, 0, stream>>>(ebuf, btot, offA, csr);

    f16* hcur = hbuf0;
    f16* hnext = hbuf1;
    for (int l = 0; l < NLAYERS; ++l) {
        k_layer<<<782, 256, 0, stream>>>(hcur, offA, csr, epsArr, gamma, beta,
                                         W1, b1, W2, b2, hnext, stats, l);
        f16* tmp = hcur; hcur = hnext; hnext = tmp;
    }
    k_pool<<<(N_NODES + 255) / 256, 256, 0, stream>>>(hcur, batch, stats,
                                                      gamma, beta, pooled);
    k_cls <<<8, 256, 0, stream>>>(pooled, Wc, bc, out);
}